// Round 2
// baseline (260.650 us; speedup 1.0000x reference)
//
#include <hip/hip_runtime.h>

// ---------------------------------------------------------------------------
// Q_DenseLayer: BN-fold int8 affine -> ReLU -> per-tensor 8b quant ->
// int8 3x3 conv (MFMA i32_16x16x64_i8) -> per-tensor 8b requant.
// Shapes: x[32,512,32,32] f32, W[128,512,3,3] f32, out y[32,128,32,32] + s_out.
//
// R2: k_conv restructured for latency: K-split (2 waves/tile, LDS combine),
// column-halo x2 layout (W'=34) + shared zero row => no conditional loads,
// 4096 waves (4/SIMD) with __launch_bounds__(256,4).
// ---------------------------------------------------------------------------

typedef int v4i __attribute__((ext_vector_type(4)));

// workspace byte offsets
#define WS_WINT  64        // 512 floats
#define WS_BINT  2176      // 512 floats
#define WS_WSC   4224      // 128 floats
#define WS_WQ    8192      // 589824 int8, layout [tap][cc(8)][co(128)][c64]
#define WS_X2    602112    // 17825792 uint8: [b][h(32)][w'(34, w+1)][c(512)]
#define WS_ZROW  18427904  // 17408 uint8 zero row (34*512)
#define X2_BYTES (17825792 + 17408)

__device__ __forceinline__ float wave_max(float m) {
#pragma unroll
    for (int off = 32; off; off >>= 1) m = fmaxf(m, __shfl_xor(m, off));
    return m;
}

// ---- kernel 1: BN fold, quantize per-channel affine, zero atomic scalars ----
__global__ __launch_bounds__(512) void k_prep_bn(
    const float* __restrict__ gamma, const float* __restrict__ beta,
    const float* __restrict__ mean,  const float* __restrict__ var,
    const float* __restrict__ asf, float* ws_f, unsigned* ws_u) {
    int t = threadIdx.x;  // 512
    float wbn = gamma[t] / sqrtf(var[t] + 1e-5f);
    float bbn = beta[t] - mean[t] * wbn;

    __shared__ float red[8];
    float m = wave_max(fabsf(wbn));
    if ((t & 63) == 0) red[t >> 6] = m;
    __syncthreads();
    float mall = red[0];
#pragma unroll
    for (int i = 1; i < 8; ++i) mall = fmaxf(mall, red[i]);

    float ws_bn = mall / 127.0f;
    float s_in  = asf[0];
    float bn_sf = ws_bn * s_in;
    float wint  = fminf(fmaxf(rintf(wbn / ws_bn), -128.f), 127.f);
    float bint  = rintf(bbn / bn_sf);
    ws_f[WS_WINT / 4 + t] = wint;
    ws_f[WS_BINT / 4 + t] = bint;
    if (t == 0) {
        ws_f[2] = bn_sf;
        ws_u[0] = 0u;  // absmax(x1) bits
        ws_u[1] = 0u;  // absmax(y) bits
    }
}

// ---- kernel 2: per-output-channel conv weight quant to int8 ----------------
// wq layout: [(tap*8 + c/64)*128 + co]*64 + (c%64)
__global__ __launch_bounds__(256) void k_prep_w(
    const float* __restrict__ cw, float* __restrict__ wsc,
    signed char* __restrict__ wq) {
    int co = blockIdx.x, t = threadIdx.x;
    const float* w = cw + (size_t)co * 4608;
    float m = 0.f;
    for (int j = t; j < 4608; j += 256) m = fmaxf(m, fabsf(w[j]));
    __shared__ float red[4];
    m = wave_max(m);
    if ((t & 63) == 0) red[t >> 6] = m;
    __syncthreads();
    float mall = fmaxf(fmaxf(red[0], red[1]), fmaxf(red[2], red[3]));
    float sc = mall / 127.0f;
    if (t == 0) wsc[co] = sc;
    for (int j = t; j < 4608; j += 256) {
        float q = fminf(fmaxf(rintf(w[j] / sc), -128.f), 127.f);
        int c = j / 9, tap = j - c * 9;  // layout [co][c][kh][kw]
        wq[(((size_t)tap * 8 + (c >> 6)) * 128 + co) * 64 + (c & 63)] = (signed char)q;
    }
}

// ---- kernel 3: global max of relu(bn-affine(x)) ---------------------------
__global__ __launch_bounds__(256) void k_xmax(
    const float4* __restrict__ x4, const float* __restrict__ asf,
    const float* __restrict__ ws_f, unsigned* __restrict__ amax) {
    float s_in  = asf[0];
    float bn_sf = ws_f[2];
    const float* wint = ws_f + WS_WINT / 4;
    const float* bint = ws_f + WS_BINT / 4;
    float m = 0.f;
    int stride = gridDim.x * blockDim.x;
    for (int i = blockIdx.x * blockDim.x + threadIdx.x; i < 4194304; i += stride) {
        float4 v = x4[i];
        int c = (i >> 8) & 511;  // 1024 elems (256 float4) per channel
        float wi = wint[c], bi = bint[c];
        float a = fmaxf(fmaf(v.x / s_in, wi, bi) * bn_sf, 0.f);
        float b = fmaxf(fmaf(v.y / s_in, wi, bi) * bn_sf, 0.f);
        float cc = fmaxf(fmaf(v.z / s_in, wi, bi) * bn_sf, 0.f);
        float d = fmaxf(fmaf(v.w / s_in, wi, bi) * bn_sf, 0.f);
        m = fmaxf(m, fmaxf(fmaxf(a, b), fmaxf(cc, d)));
    }
    __shared__ float red[4];
    m = wave_max(m);
    if ((threadIdx.x & 63) == 0) red[threadIdx.x >> 6] = m;
    __syncthreads();
    if (threadIdx.x == 0) {
        m = fmaxf(fmaxf(red[0], red[1]), fmaxf(red[2], red[3]));
        atomicMax(amax, __float_as_uint(m));
    }
}

// ---- kernel 4: quantize x to int8 NHWC-with-column-halo (LDS transpose) ----
// one block per (b, h): reads x[b, :, h, :] (NCHW), writes x2[b, h, w+1, c]
__global__ __launch_bounds__(256) void k_xquant(
    const float4* __restrict__ x4, const float* __restrict__ asf,
    const float* __restrict__ ws_f, const unsigned* __restrict__ amax,
    unsigned* __restrict__ x2u) {
    int bb = blockIdx.x >> 5, h = blockIdx.x & 31;
    float s_in  = asf[0];
    float bn_sf = ws_f[2];
    float s_act = __uint_as_float(amax[0]) / 127.0f;
    const float* wint = ws_f + WS_WINT / 4;
    const float* bint = ws_f + WS_BINT / 4;
    int t = threadIdx.x;

    __shared__ unsigned lds[512 * 9];  // row stride 9 dwords (8 data + 1 pad)

#pragma unroll
    for (int it = 0; it < 16; ++it) {
        int idx = it * 256 + t;
        int c = idx >> 3, f4 = idx & 7;
        float4 v = x4[((size_t)bb * 512 + c) * 256 + h * 8 + f4];
        float wi = wint[c], bi = bint[c];
        unsigned q0 = (unsigned)(int)fminf(rintf(fmaxf(fmaf(v.x / s_in, wi, bi) * bn_sf, 0.f) / s_act), 127.f);
        unsigned q1 = (unsigned)(int)fminf(rintf(fmaxf(fmaf(v.y / s_in, wi, bi) * bn_sf, 0.f) / s_act), 127.f);
        unsigned q2 = (unsigned)(int)fminf(rintf(fmaxf(fmaf(v.z / s_in, wi, bi) * bn_sf, 0.f) / s_act), 127.f);
        unsigned q3 = (unsigned)(int)fminf(rintf(fmaxf(fmaf(v.w / s_in, wi, bi) * bn_sf, 0.f) / s_act), 127.f);
        lds[c * 9 + f4] = q0 | (q1 << 8) | (q2 << 16) | (q3 << 24);
    }
    __syncthreads();

    // phase 2: gather 4 channel-dwords, 4x4 byte transpose, write halo-NHWC
#pragma unroll
    for (int it2 = 0; it2 < 4; ++it2) {
        int cdw = (t & 31) + ((t >> 6) << 5);          // 0..127
        int wq4 = ((t >> 5) & 1) + (it2 << 1);         // 0..7
        unsigned u0 = lds[(4 * cdw + 0) * 9 + wq4];
        unsigned u1 = lds[(4 * cdw + 1) * 9 + wq4];
        unsigned u2 = lds[(4 * cdw + 2) * 9 + wq4];
        unsigned u3 = lds[(4 * cdw + 3) * 9 + wq4];
        // dword addr: ((b*32 + h)*34 + (w+1))*128 + cdw,  w = wq4*4 + k
        unsigned* dst = x2u + ((size_t)((bb * 32 + h) * 34 + wq4 * 4 + 1)) * 128 + cdw;
#pragma unroll
        for (int k = 0; k < 4; ++k) {
            unsigned o = ((u0 >> (8 * k)) & 255) | (((u1 >> (8 * k)) & 255) << 8) |
                         (((u2 >> (8 * k)) & 255) << 16) | (((u3 >> (8 * k)) & 255) << 24);
            dst[(size_t)k * 128] = o;
        }
    }
}

// ---- kernel 5: int8 3x3 conv via MFMA, K-split + LDS combine, fused y-max --
// block = one (b,h) row, 4 waves: (co-half, K-half). wave tile 32px x 64co.
// grid 1024 blocks -> 4096 waves = 4 waves/SIMD.
__global__ __launch_bounds__(256, 4) void k_conv(
    const unsigned char* __restrict__ x2, const unsigned char* __restrict__ zrow,
    const signed char* __restrict__ wq,
    const float* __restrict__ wsc, const unsigned* __restrict__ amax,
    unsigned* __restrict__ amaxy, float* __restrict__ y) {
    __shared__ v4i red[2][512];  // 16 KB: K-half partial tiles per co-half
    int t = threadIdx.x;
    int lane = t & 63, wv = t >> 6;
    int ch = wv & 1;              // co half
    int kv = wv >> 1;             // K half (channel chunks ccg = kv*4 .. kv*4+3)
    int bb = blockIdx.x >> 5, h = blockIdx.x & 31;
    int m = lane & 15, quad = lane >> 4;
    int co0 = ch * 64;

    v4i acc[2][4];
#pragma unroll
    for (int i = 0; i < 2; ++i)
#pragma unroll
        for (int j = 0; j < 4; ++j) acc[i][j] = (v4i){0, 0, 0, 0};

    const unsigned char* xb = x2 + (size_t)bb * (32 * 34 * 512);

#pragma unroll
    for (int kh = 0; kh < 3; ++kh) {
        int h2 = h + kh - 1;
        const unsigned char* rowp = ((unsigned)h2 < 32u) ? (xb + (size_t)h2 * (34 * 512)) : zrow;
#pragma unroll
        for (int kw = 0; kw < 3; ++kw) {
            int tap = kh * 3 + kw;
            const v4i* pa = (const v4i*)(rowp + (m + kw) * 512 + kv * 256 + quad * 16);
            const v4i* pb = (const v4i*)(rowp + (m + 16 + kw) * 512 + kv * 256 + quad * 16);
            const v4i* pw = (const v4i*)(wq + ((size_t)((tap * 8 + kv * 4) * 128) + co0 + m) * 64 + quad * 16);
#pragma unroll
            for (int cc = 0; cc < 4; ++cc) {
                v4i a0 = pa[cc * 4];           // +cc*64 bytes (channel chunk)
                v4i a1 = pb[cc * 4];
#pragma unroll
                for (int nt = 0; nt < 4; ++nt) {
                    v4i bf = pw[cc * 512 + nt * 64];  // +cc*8KB, +nt*1KB
                    acc[0][nt] = __builtin_amdgcn_mfma_i32_16x16x64_i8(a0, bf, acc[0][nt], 0, 0, 0);
                    acc[1][nt] = __builtin_amdgcn_mfma_i32_16x16x64_i8(a1, bf, acc[1][nt], 0, 0, 0);
                }
            }
        }
    }

    // combine K halves through LDS
    if (kv == 1) {
#pragma unroll
        for (int i = 0; i < 2; ++i)
#pragma unroll
            for (int nt = 0; nt < 4; ++nt)
                red[ch][(i * 4 + nt) * 64 + lane] = acc[i][nt];
    }
    __syncthreads();
    if (kv == 0) {
#pragma unroll
        for (int i = 0; i < 2; ++i)
#pragma unroll
            for (int nt = 0; nt < 4; ++nt) {
                v4i p = red[ch][(i * 4 + nt) * 64 + lane];
                acc[i][nt].x += p.x; acc[i][nt].y += p.y;
                acc[i][nt].z += p.z; acc[i][nt].w += p.w;
            }

        // epilogue: y = y_int * (s_act * ws_c[co]); C layout: col(lane&15)=co, row(quad*4+reg)=w
        float s_act = __uint_as_float(amax[0]) / 127.0f;
        float mx = 0.f;
#pragma unroll
        for (int nt = 0; nt < 4; ++nt) {
            int co = co0 + nt * 16 + m;
            float sf = s_act * wsc[co];
            float* yb = y + ((size_t)(bb * 128 + co)) * 1024 + h * 32;
#pragma unroll
            for (int rr = 0; rr < 4; ++rr) {
                int w = quad * 4 + rr;
                float v0 = (float)acc[0][nt][rr] * sf;
                float v1 = (float)acc[1][nt][rr] * sf;
                yb[w] = v0;
                yb[w + 16] = v1;
                mx = fmaxf(mx, fmaxf(fabsf(v0), fabsf(v1)));
            }
        }
        mx = wave_max(mx);
        if (lane == 0) atomicMax(amaxy, __float_as_uint(mx));
    }
}

// ---- kernel 6: final requant in place + write s_out -----------------------
__global__ __launch_bounds__(256) void k_yquant(float* __restrict__ yout,
                                                const unsigned* __restrict__ ws_u) {
    float s_out = __uint_as_float(ws_u[1]) / 127.0f;
    float4* y4 = (float4*)yout;
    int stride = gridDim.x * blockDim.x;
    for (int i = blockIdx.x * blockDim.x + threadIdx.x; i < 1048576; i += stride) {
        float4 v = y4[i];
        v.x = fminf(fmaxf(rintf(v.x / s_out), -128.f), 127.f) * s_out;
        v.y = fminf(fmaxf(rintf(v.y / s_out), -128.f), 127.f) * s_out;
        v.z = fminf(fmaxf(rintf(v.z / s_out), -128.f), 127.f) * s_out;
        v.w = fminf(fmaxf(rintf(v.w / s_out), -128.f), 127.f) * s_out;
        y4[i] = v;
    }
    if (blockIdx.x == 0 && threadIdx.x == 0) yout[4194304] = s_out;
}

extern "C" void kernel_launch(void* const* d_in, const int* in_sizes, int n_in,
                              void* d_out, int out_size, void* d_ws, size_t ws_size,
                              hipStream_t stream) {
    const float* x     = (const float*)d_in[0];
    const float* asf   = (const float*)d_in[1];
    const float* gamma = (const float*)d_in[2];
    const float* beta  = (const float*)d_in[3];
    const float* mean  = (const float*)d_in[4];
    const float* var   = (const float*)d_in[5];
    const float* cw    = (const float*)d_in[6];

    float*    ws_f = (float*)d_ws;
    unsigned* ws_u = (unsigned*)d_ws;
    signed char*   wq   = (signed char*)d_ws + WS_WQ;
    unsigned char* x2   = (unsigned char*)d_ws + WS_X2;
    unsigned char* zrow = (unsigned char*)d_ws + WS_ZROW;
    float* y = (float*)d_out;

    // zero halo columns + zero row (ws is re-poisoned to 0xAA before each call)
    hipMemsetAsync(x2, 0, X2_BYTES, stream);

    k_prep_bn<<<1, 512, 0, stream>>>(gamma, beta, mean, var, asf, ws_f, ws_u);
    k_prep_w<<<128, 256, 0, stream>>>(cw, ws_f + WS_WSC / 4, wq);
    k_xmax<<<2048, 256, 0, stream>>>((const float4*)x, asf, ws_f, ws_u);
    k_xquant<<<1024, 256, 0, stream>>>((const float4*)x, asf, ws_f, ws_u, (unsigned*)x2);
    k_conv<<<1024, 256, 0, stream>>>(x2, zrow, wq, ws_f + WS_WSC / 4, ws_u, ws_u + 1, y);
    k_yquant<<<1024, 256, 0, stream>>>(y, ws_u);
}

// Round 3
// 237.047 us; speedup vs baseline: 1.0996x; 1.0996x over previous
//
#include <hip/hip_runtime.h>

// ---------------------------------------------------------------------------
// Q_DenseLayer: BN-fold int8 affine -> ReLU -> per-tensor 8b quant ->
// int8 3x3 conv (MFMA i32_16x16x64_i8) -> per-tensor 8b requant.
// Shapes: x[32,512,32,32] f32, W[128,512,3,3] f32, out y[32,128,32,32] + s_out.
//
// R3: x2 chunk-major layout [b][h][cc8][w'34][c64] => every conv load is a
// lane-contiguous 1KB dwordx4; wave tile 64px x 64co (4x4 MFMA tiles);
// 4-way K-split per block with 2-round LDS tree combine; XCD-swizzled tiles.
// ---------------------------------------------------------------------------

typedef int v4i __attribute__((ext_vector_type(4)));

// workspace byte offsets
#define WS_WINT  64        // 512 floats
#define WS_BINT  2176      // 512 floats
#define WS_WSC   4224      // 128 floats
#define WS_WQ    8192      // 589824 int8, layout [tap][cc(8)][co(128)][c64]
#define WS_X2    602112    // 17825792 uint8: [b][h(32)][cc(8)][w'(34)][c64]
#define WS_ZROW  18427904  // 17408 uint8 zero row (8*34*64)
#define X2_BYTES (17825792 + 17408)

__device__ __forceinline__ float wave_max(float m) {
#pragma unroll
    for (int off = 32; off; off >>= 1) m = fmaxf(m, __shfl_xor(m, off));
    return m;
}

// ---- kernel 1: BN fold, quantize per-channel affine, zero atomic scalars ----
__global__ __launch_bounds__(512) void k_prep_bn(
    const float* __restrict__ gamma, const float* __restrict__ beta,
    const float* __restrict__ mean,  const float* __restrict__ var,
    const float* __restrict__ asf, float* ws_f, unsigned* ws_u) {
    int t = threadIdx.x;  // 512
    float wbn = gamma[t] / sqrtf(var[t] + 1e-5f);
    float bbn = beta[t] - mean[t] * wbn;

    __shared__ float red[8];
    float m = wave_max(fabsf(wbn));
    if ((t & 63) == 0) red[t >> 6] = m;
    __syncthreads();
    float mall = red[0];
#pragma unroll
    for (int i = 1; i < 8; ++i) mall = fmaxf(mall, red[i]);

    float ws_bn = mall / 127.0f;
    float s_in  = asf[0];
    float bn_sf = ws_bn * s_in;
    float wint  = fminf(fmaxf(rintf(wbn / ws_bn), -128.f), 127.f);
    float bint  = rintf(bbn / bn_sf);
    ws_f[WS_WINT / 4 + t] = wint;
    ws_f[WS_BINT / 4 + t] = bint;
    if (t == 0) {
        ws_f[2] = bn_sf;
        ws_u[0] = 0u;  // absmax(x1) bits
        ws_u[1] = 0u;  // absmax(y) bits
    }
}

// ---- kernel 2: per-output-channel conv weight quant to int8 ----------------
// wq layout: [(tap*8 + c/64)*128 + co]*64 + (c%64)
__global__ __launch_bounds__(256) void k_prep_w(
    const float* __restrict__ cw, float* __restrict__ wsc,
    signed char* __restrict__ wq) {
    int co = blockIdx.x, t = threadIdx.x;
    const float* w = cw + (size_t)co * 4608;
    float m = 0.f;
    for (int j = t; j < 4608; j += 256) m = fmaxf(m, fabsf(w[j]));
    __shared__ float red[4];
    m = wave_max(m);
    if ((t & 63) == 0) red[t >> 6] = m;
    __syncthreads();
    float mall = fmaxf(fmaxf(red[0], red[1]), fmaxf(red[2], red[3]));
    float sc = mall / 127.0f;
    if (t == 0) wsc[co] = sc;
    for (int j = t; j < 4608; j += 256) {
        float q = fminf(fmaxf(rintf(w[j] / sc), -128.f), 127.f);
        int c = j / 9, tap = j - c * 9;  // layout [co][c][kh][kw]
        wq[(((size_t)tap * 8 + (c >> 6)) * 128 + co) * 64 + (c & 63)] = (signed char)q;
    }
}

// ---- kernel 3: global max of relu(bn-affine(x)) ---------------------------
__global__ __launch_bounds__(256) void k_xmax(
    const float4* __restrict__ x4, const float* __restrict__ asf,
    const float* __restrict__ ws_f, unsigned* __restrict__ amax) {
    float s_in  = asf[0];
    float bn_sf = ws_f[2];
    const float* wint = ws_f + WS_WINT / 4;
    const float* bint = ws_f + WS_BINT / 4;
    float m = 0.f;
    int stride = gridDim.x * blockDim.x;
    for (int i = blockIdx.x * blockDim.x + threadIdx.x; i < 4194304; i += stride) {
        float4 v = x4[i];
        int c = (i >> 8) & 511;  // 1024 elems (256 float4) per channel
        float wi = wint[c], bi = bint[c];
        float a = fmaxf(fmaf(v.x / s_in, wi, bi) * bn_sf, 0.f);
        float b = fmaxf(fmaf(v.y / s_in, wi, bi) * bn_sf, 0.f);
        float cc = fmaxf(fmaf(v.z / s_in, wi, bi) * bn_sf, 0.f);
        float d = fmaxf(fmaf(v.w / s_in, wi, bi) * bn_sf, 0.f);
        m = fmaxf(m, fmaxf(fmaxf(a, b), fmaxf(cc, d)));
    }
    __shared__ float red[4];
    m = wave_max(m);
    if ((threadIdx.x & 63) == 0) red[threadIdx.x >> 6] = m;
    __syncthreads();
    if (threadIdx.x == 0) {
        m = fmaxf(fmaxf(red[0], red[1]), fmaxf(red[2], red[3]));
        atomicMax(amax, __float_as_uint(m));
    }
}

// ---- kernel 4: quantize x to int8 chunk-major halo layout ------------------
// one block per (b, h): reads x[b, :, h, :] (NCHW), writes x2[b][h][cc][w+1][c64]
__global__ __launch_bounds__(256) void k_xquant(
    const float4* __restrict__ x4, const float* __restrict__ asf,
    const float* __restrict__ ws_f, const unsigned* __restrict__ amax,
    unsigned* __restrict__ x2u) {
    int bb = blockIdx.x >> 5, h = blockIdx.x & 31;
    float s_in  = asf[0];
    float bn_sf = ws_f[2];
    float s_act = __uint_as_float(amax[0]) / 127.0f;
    const float* wint = ws_f + WS_WINT / 4;
    const float* bint = ws_f + WS_BINT / 4;
    int t = threadIdx.x;

    __shared__ unsigned lds[512 * 9];  // row stride 9 dwords (8 data + 1 pad)

#pragma unroll
    for (int it = 0; it < 16; ++it) {
        int idx = it * 256 + t;
        int c = idx >> 3, f4 = idx & 7;
        float4 v = x4[((size_t)bb * 512 + c) * 256 + h * 8 + f4];
        float wi = wint[c], bi = bint[c];
        unsigned q0 = (unsigned)(int)fminf(rintf(fmaxf(fmaf(v.x / s_in, wi, bi) * bn_sf, 0.f) / s_act), 127.f);
        unsigned q1 = (unsigned)(int)fminf(rintf(fmaxf(fmaf(v.y / s_in, wi, bi) * bn_sf, 0.f) / s_act), 127.f);
        unsigned q2 = (unsigned)(int)fminf(rintf(fmaxf(fmaf(v.z / s_in, wi, bi) * bn_sf, 0.f) / s_act), 127.f);
        unsigned q3 = (unsigned)(int)fminf(rintf(fmaxf(fmaf(v.w / s_in, wi, bi) * bn_sf, 0.f) / s_act), 127.f);
        lds[c * 9 + f4] = q0 | (q1 << 8) | (q2 << 16) | (q3 << 24);
    }
    __syncthreads();

    // phase 2: gather 4 channel-dwords, 4x4 byte transpose, write chunk-major
#pragma unroll
    for (int it2 = 0; it2 < 4; ++it2) {
        int cdw = (t & 31) + ((t >> 6) << 5);          // channel dword 0..127
        int wq4 = ((t >> 5) & 1) + (it2 << 1);         // 0..7
        unsigned u0 = lds[(4 * cdw + 0) * 9 + wq4];
        unsigned u1 = lds[(4 * cdw + 1) * 9 + wq4];
        unsigned u2 = lds[(4 * cdw + 2) * 9 + wq4];
        unsigned u3 = lds[(4 * cdw + 3) * 9 + wq4];
        int cc = cdw >> 4, inner = cdw & 15;
        // dword addr: (((b*32+h)*8 + cc)*34 + (w+1))*16 + inner,  w = wq4*4+k
        unsigned* dst = x2u + ((size_t)(((bb * 32 + h) * 8 + cc) * 34 + wq4 * 4 + 1)) * 16 + inner;
#pragma unroll
        for (int k = 0; k < 4; ++k) {
            unsigned o = ((u0 >> (8 * k)) & 255) | (((u1 >> (8 * k)) & 255) << 8) |
                         (((u2 >> (8 * k)) & 255) << 16) | (((u3 >> (8 * k)) & 255) << 24);
            dst[(size_t)k * 16] = o;
        }
    }
}

// ---- kernel 5: int8 3x3 conv via MFMA -------------------------------------
// block = one tile (64px = rows h0,h0+1; 64co) x 4 K-quarter waves.
// All loads lane-contiguous 1KB. 1024 blocks, 4096 waves (4/SIMD).
__global__ __launch_bounds__(256, 4) void k_conv(
    const unsigned char* __restrict__ x2, const unsigned char* __restrict__ zrow,
    const signed char* __restrict__ wq,
    const float* __restrict__ wsc, const unsigned* __restrict__ amax,
    unsigned* __restrict__ amaxy, float* __restrict__ y) {
    __shared__ v4i red[2][1024];  // 32 KB, two partial-tile regions
    int t = threadIdx.x;
    int lane = t & 63, kv = t >> 6;          // kv = K quarter 0..3
    int m = lane & 15, quad = lane >> 4;

    int bid = blockIdx.x;
    int tile = (bid & 7) * 128 + (bid >> 3); // XCD swizzle: 128 tiles per XCD
    int ch = tile & 1;                       // co half
    int rowpair = (tile >> 1) & 15;
    int bb = tile >> 5;
    int h0 = rowpair * 2;
    int co0 = ch * 64;

    const unsigned char* xb = x2 + (size_t)bb * (32 * 8 * 34 * 64);
    const unsigned char* rp[4];
#pragma unroll
    for (int j = 0; j < 4; ++j) {
        int row = h0 - 1 + j;
        rp[j] = ((unsigned)row < 32u) ? (xb + (size_t)row * (8 * 34 * 64)) : zrow;
    }

    v4i acc[4][4];
#pragma unroll
    for (int i = 0; i < 4; ++i)
#pragma unroll
        for (int j = 0; j < 4; ++j) acc[i][j] = (v4i){0, 0, 0, 0};

    const v4i* pwv = (const v4i*)wq + (co0 + m) * 4 + quad;

#pragma unroll
    for (int kh = 0; kh < 3; ++kh)
#pragma unroll
        for (int kw = 0; kw < 3; ++kw) {
            int tap = kh * 3 + kw;
#pragma unroll
            for (int cc = 0; cc < 2; ++cc) {
                int ci = kv * 2 + cc;        // channel chunk 0..7
                v4i a[4];
#pragma unroll
                for (int mt = 0; mt < 4; ++mt)
                    a[mt] = *((const v4i*)rp[kh + (mt >> 1)] +
                              (ci * 34 + m + (mt & 1) * 16 + kw) * 4 + quad);
#pragma unroll
                for (int nt = 0; nt < 4; ++nt) {
                    v4i bf = pwv[tap * 4096 + ci * 512 + nt * 64];
#pragma unroll
                    for (int mt = 0; mt < 4; ++mt)
                        acc[mt][nt] = __builtin_amdgcn_mfma_i32_16x16x64_i8(a[mt], bf, acc[mt][nt], 0, 0, 0);
                }
            }
        }

    // 2-round LDS tree combine of the 4 K-quarters
    if (kv >= 2) {
#pragma unroll
        for (int mt = 0; mt < 4; ++mt)
#pragma unroll
            for (int nt = 0; nt < 4; ++nt)
                red[kv - 2][(mt * 4 + nt) * 64 + lane] = acc[mt][nt];
    }
    __syncthreads();
    if (kv < 2) {
#pragma unroll
        for (int mt = 0; mt < 4; ++mt)
#pragma unroll
            for (int nt = 0; nt < 4; ++nt) {
                v4i p = red[kv][(mt * 4 + nt) * 64 + lane];
                acc[mt][nt].x += p.x; acc[mt][nt].y += p.y;
                acc[mt][nt].z += p.z; acc[mt][nt].w += p.w;
            }
    }
    __syncthreads();
    if (kv == 1) {
#pragma unroll
        for (int mt = 0; mt < 4; ++mt)
#pragma unroll
            for (int nt = 0; nt < 4; ++nt)
                red[0][(mt * 4 + nt) * 64 + lane] = acc[mt][nt];
    }
    __syncthreads();
    if (kv == 0) {
#pragma unroll
        for (int mt = 0; mt < 4; ++mt)
#pragma unroll
            for (int nt = 0; nt < 4; ++nt) {
                v4i p = red[0][(mt * 4 + nt) * 64 + lane];
                acc[mt][nt].x += p.x; acc[mt][nt].y += p.y;
                acc[mt][nt].z += p.z; acc[mt][nt].w += p.w;
            }

        // epilogue: C layout col(lane&15)=co-within-ntile, row(quad*4+reg)=w
        float s_act = __uint_as_float(amax[0]) / 127.0f;
        float mx = 0.f;
#pragma unroll
        for (int nt = 0; nt < 4; ++nt) {
            int co = co0 + nt * 16 + m;
            float sf = s_act * wsc[co];
#pragma unroll
            for (int mt = 0; mt < 4; ++mt) {
                int row = h0 + (mt >> 1);
                float* yb = y + ((size_t)(bb * 128 + co)) * 1024 + row * 32 + (mt & 1) * 16;
#pragma unroll
                for (int rr = 0; rr < 4; ++rr) {
                    float v0 = (float)acc[mt][nt][rr] * sf;
                    yb[quad * 4 + rr] = v0;
                    mx = fmaxf(mx, fabsf(v0));
                }
            }
        }
        mx = wave_max(mx);
        if (lane == 0) atomicMax(amaxy, __float_as_uint(mx));
    }
}

// ---- kernel 6: final requant in place + write s_out -----------------------
__global__ __launch_bounds__(256) void k_yquant(float* __restrict__ yout,
                                                const unsigned* __restrict__ ws_u) {
    float s_out = __uint_as_float(ws_u[1]) / 127.0f;
    float4* y4 = (float4*)yout;
    int stride = gridDim.x * blockDim.x;
    for (int i = blockIdx.x * blockDim.x + threadIdx.x; i < 1048576; i += stride) {
        float4 v = y4[i];
        v.x = fminf(fmaxf(rintf(v.x / s_out), -128.f), 127.f) * s_out;
        v.y = fminf(fmaxf(rintf(v.y / s_out), -128.f), 127.f) * s_out;
        v.z = fminf(fmaxf(rintf(v.z / s_out), -128.f), 127.f) * s_out;
        v.w = fminf(fmaxf(rintf(v.w / s_out), -128.f), 127.f) * s_out;
        y4[i] = v;
    }
    if (blockIdx.x == 0 && threadIdx.x == 0) yout[4194304] = s_out;
}

extern "C" void kernel_launch(void* const* d_in, const int* in_sizes, int n_in,
                              void* d_out, int out_size, void* d_ws, size_t ws_size,
                              hipStream_t stream) {
    const float* x     = (const float*)d_in[0];
    const float* asf   = (const float*)d_in[1];
    const float* gamma = (const float*)d_in[2];
    const float* beta  = (const float*)d_in[3];
    const float* mean  = (const float*)d_in[4];
    const float* var   = (const float*)d_in[5];
    const float* cw    = (const float*)d_in[6];

    float*    ws_f = (float*)d_ws;
    unsigned* ws_u = (unsigned*)d_ws;
    signed char*   wq   = (signed char*)d_ws + WS_WQ;
    unsigned char* x2   = (unsigned char*)d_ws + WS_X2;
    unsigned char* zrow = (unsigned char*)d_ws + WS_ZROW;
    float* y = (float*)d_out;

    // zero halo columns + zero row (ws is re-poisoned to 0xAA before each call)
    hipMemsetAsync(x2, 0, X2_BYTES, stream);

    k_prep_bn<<<1, 512, 0, stream>>>(gamma, beta, mean, var, asf, ws_f, ws_u);
    k_prep_w<<<128, 256, 0, stream>>>(cw, ws_f + WS_WSC / 4, wq);
    k_xmax<<<2048, 256, 0, stream>>>((const float4*)x, asf, ws_f, ws_u);
    k_xquant<<<1024, 256, 0, stream>>>((const float4*)x, asf, ws_f, ws_u, (unsigned*)x2);
    k_conv<<<1024, 256, 0, stream>>>(x2, zrow, wq, ws_f + WS_WSC / 4, ws_u, ws_u + 1, y);
    k_yquant<<<1024, 256, 0, stream>>>(y, ws_u);
}

// Round 4
// 184.681 us; speedup vs baseline: 1.4113x; 1.2835x over previous
//
#include <hip/hip_runtime.h>

// ---------------------------------------------------------------------------
// Q_DenseLayer: BN-fold int8 affine -> ReLU -> per-tensor 8b quant ->
// int8 3x3 conv (MFMA i32_16x16x64_i8) -> per-tensor 8b requant.
// Shapes: x[32,512,32,32] f32, W[128,512,3,3] f32, out y[32,128,32,32] + s_out.
//
// R4: fix R3's accumulator spill (__launch_bounds__(256,2): 256-reg budget;
// R3's (256,4)=128 regs spilled 64 acc regs -> 69MB scratch traffic).
// Fold BN+quant scales into per-channel FMA (no per-element v_div).
// Fuse prep kernels; replace 17.8MB memset with targeted halo zeroing.
// ---------------------------------------------------------------------------

typedef int v4i __attribute__((ext_vector_type(4)));

// workspace byte offsets
#define WS_A1    64        // 512 floats: A1_c = w_int*bn_sf/s_in
#define WS_B1    2176      // 512 floats: B1_c = b_int*bn_sf
#define WS_WSC   4224      // 128 floats
#define WS_WQ    8192      // 589824 int8, layout [tap][cc(8)][co(128)][c64]
#define WS_X2    602112    // 17825792 uint8: [b][h(32)][cc(8)][w'(34)][c64]
#define WS_ZROW  18427904  // 17408 uint8 zero row (8*34*64)

__device__ __forceinline__ float wave_max(float m) {
#pragma unroll
    for (int off = 32; off; off >>= 1) m = fmaxf(m, __shfl_xor(m, off));
    return m;
}

// ---- kernel 1: fused prep. block 128: BN fold; blocks 0..127: conv-w quant --
__global__ __launch_bounds__(512) void k_prep(
    const float* __restrict__ gamma, const float* __restrict__ beta,
    const float* __restrict__ mean,  const float* __restrict__ var,
    const float* __restrict__ asf,   const float* __restrict__ cw,
    float* ws_f, unsigned* ws_u, float* __restrict__ wsc,
    signed char* __restrict__ wq) {
    int t = threadIdx.x;
    __shared__ float red[8];
    if (blockIdx.x == 128) {
        float wbn = gamma[t] / sqrtf(var[t] + 1e-5f);
        float bbn = beta[t] - mean[t] * wbn;
        float m = wave_max(fabsf(wbn));
        if ((t & 63) == 0) red[t >> 6] = m;
        __syncthreads();
        float mall = red[0];
#pragma unroll
        for (int i = 1; i < 8; ++i) mall = fmaxf(mall, red[i]);
        float ws_bn = mall / 127.0f;
        float s_in  = asf[0];
        float bn_sf = ws_bn * s_in;
        float wint  = fminf(fmaxf(rintf(wbn / ws_bn), -128.f), 127.f);
        float bint  = rintf(bbn / bn_sf);
        ws_f[WS_A1 / 4 + t] = wint * bn_sf / s_in;  // x1 = fmaf(x, A1, B1)
        ws_f[WS_B1 / 4 + t] = bint * bn_sf;
        if (t == 0) { ws_u[0] = 0u; ws_u[1] = 0u; }
    } else {
        int co = blockIdx.x;
        const float* w = cw + (size_t)co * 4608;
        float m = 0.f;
        for (int j = t; j < 4608; j += 512) m = fmaxf(m, fabsf(w[j]));
        m = wave_max(m);
        if ((t & 63) == 0) red[t >> 6] = m;
        __syncthreads();
        float mall = red[0];
#pragma unroll
        for (int i = 1; i < 8; ++i) mall = fmaxf(mall, red[i]);
        float sc = mall / 127.0f;
        if (t == 0) wsc[co] = sc;
        for (int j = t; j < 4608; j += 512) {
            float q = fminf(fmaxf(rintf(w[j] / sc), -128.f), 127.f);
            int c = j / 9, tap = j - c * 9;  // layout [co][c][kh][kw]
            wq[(((size_t)tap * 8 + (c >> 6)) * 128 + co) * 64 + (c & 63)] = (signed char)q;
        }
    }
}

// ---- kernel 2: global max of relu(bn-affine(x)) = max(0, max fmaf) ---------
__global__ __launch_bounds__(256) void k_xmax(
    const float4* __restrict__ x4, const float* __restrict__ ws_f,
    unsigned* __restrict__ amax) {
    const float* A1 = ws_f + WS_A1 / 4;
    const float* B1 = ws_f + WS_B1 / 4;
    float m = 0.f;  // >= 0, so relu is implicit
    int stride = gridDim.x * blockDim.x;
    for (int i = blockIdx.x * blockDim.x + threadIdx.x; i < 4194304; i += stride) {
        float4 v = x4[i];
        int c = (i >> 8) & 511;  // 256 float4 per (b,c)
        float A = A1[c], B = B1[c];
        m = fmaxf(m, fmaxf(fmaxf(fmaf(v.x, A, B), fmaf(v.y, A, B)),
                           fmaxf(fmaf(v.z, A, B), fmaf(v.w, A, B))));
    }
    __shared__ float red[4];
    m = wave_max(m);
    if ((threadIdx.x & 63) == 0) red[threadIdx.x >> 6] = m;
    __syncthreads();
    if (threadIdx.x == 0) {
        m = fmaxf(fmaxf(red[0], red[1]), fmaxf(red[2], red[3]));
        atomicMax(amax, __float_as_uint(m));
    }
}

// ---- kernel 3: quantize x to int8 chunk-major halo layout ------------------
// one block per (b, h); also zeroes its own halo columns + shared zero row.
__global__ __launch_bounds__(256) void k_xquant(
    const float4* __restrict__ x4, const float* __restrict__ ws_f,
    const unsigned* __restrict__ amax, unsigned* __restrict__ x2u,
    unsigned* __restrict__ zrowu) {
    int bb = blockIdx.x >> 5, h = blockIdx.x & 31;
    float inv_sact = 127.0f / __uint_as_float(amax[0]);
    const float* A1 = ws_f + WS_A1 / 4;
    const float* B1 = ws_f + WS_B1 / 4;
    int t = threadIdx.x;

    // zero halo columns w'=0 and w'=33 for this (bb,h): 8cc x 2 x 64B
    {
        int cc = t >> 5, rem = t & 31;
        int wp = (rem >> 4) * 33, inner = rem & 15;
        x2u[((size_t)(((bb * 32 + h) * 8 + cc) * 34 + wp)) * 16 + inner] = 0u;
    }
    // zero the shared zero-row (17408 B) using blocks 0..16
    if (blockIdx.x < 17) {
        int idx = blockIdx.x * 256 + t;
        if (idx < 4352) zrowu[idx] = 0u;
    }

    __shared__ unsigned lds[512 * 9];  // row stride 9 dwords (8 data + 1 pad)

#pragma unroll
    for (int it = 0; it < 16; ++it) {
        int idx = it * 256 + t;
        int c = idx >> 3, f4 = idx & 7;
        float4 v = x4[((size_t)bb * 512 + c) * 256 + h * 8 + f4];
        float A = A1[c] * inv_sact, B = B1[c] * inv_sact;
        unsigned q0 = (unsigned)(int)fminf(rintf(fmaxf(fmaf(v.x, A, B), 0.f)), 127.f);
        unsigned q1 = (unsigned)(int)fminf(rintf(fmaxf(fmaf(v.y, A, B), 0.f)), 127.f);
        unsigned q2 = (unsigned)(int)fminf(rintf(fmaxf(fmaf(v.z, A, B), 0.f)), 127.f);
        unsigned q3 = (unsigned)(int)fminf(rintf(fmaxf(fmaf(v.w, A, B), 0.f)), 127.f);
        lds[c * 9 + f4] = q0 | (q1 << 8) | (q2 << 16) | (q3 << 24);
    }
    __syncthreads();

    // phase 2: gather 4 channel-dwords, 4x4 byte transpose, write chunk-major
#pragma unroll
    for (int it2 = 0; it2 < 4; ++it2) {
        int cdw = (t & 31) + ((t >> 6) << 5);          // channel dword 0..127
        int wq4 = ((t >> 5) & 1) + (it2 << 1);         // 0..7
        unsigned u0 = lds[(4 * cdw + 0) * 9 + wq4];
        unsigned u1 = lds[(4 * cdw + 1) * 9 + wq4];
        unsigned u2 = lds[(4 * cdw + 2) * 9 + wq4];
        unsigned u3 = lds[(4 * cdw + 3) * 9 + wq4];
        int cc = cdw >> 4, inner = cdw & 15;
        // dword addr: (((b*32+h)*8 + cc)*34 + (w+1))*16 + inner,  w = wq4*4+k
        unsigned* dst = x2u + ((size_t)(((bb * 32 + h) * 8 + cc) * 34 + wq4 * 4 + 1)) * 16 + inner;
#pragma unroll
        for (int k = 0; k < 4; ++k) {
            unsigned o = ((u0 >> (8 * k)) & 255) | (((u1 >> (8 * k)) & 255) << 8) |
                         (((u2 >> (8 * k)) & 255) << 16) | (((u3 >> (8 * k)) & 255) << 24);
            dst[(size_t)k * 16] = o;
        }
    }
}

// ---- kernel 4: int8 3x3 conv via MFMA -------------------------------------
// block = one tile (64px = rows h0,h0+1; 64co) x 4 K-quarter waves.
// launch_bounds(256,2): 256-reg budget, NO spill (R3's (256,4) spilled acc).
__global__ __launch_bounds__(256, 2) void k_conv(
    const unsigned char* __restrict__ x2, const unsigned char* __restrict__ zrow,
    const signed char* __restrict__ wq,
    const float* __restrict__ wsc, const unsigned* __restrict__ amax,
    unsigned* __restrict__ amaxy, float* __restrict__ y) {
    __shared__ v4i red[2][1024];  // 32 KB, two partial-tile regions
    int t = threadIdx.x;
    int lane = t & 63, kv = t >> 6;          // kv = K quarter 0..3
    int m = lane & 15, quad = lane >> 4;

    int bid = blockIdx.x;
    int tile = (bid & 7) * 128 + (bid >> 3); // XCD swizzle: 128 tiles per XCD
    int ch = tile & 1;                       // co half
    int rowpair = (tile >> 1) & 15;
    int bb = tile >> 5;
    int h0 = rowpair * 2;
    int co0 = ch * 64;

    const unsigned char* xb = x2 + (size_t)bb * (32 * 8 * 34 * 64);
    const unsigned char* rp[4];
#pragma unroll
    for (int j = 0; j < 4; ++j) {
        int row = h0 - 1 + j;
        rp[j] = ((unsigned)row < 32u) ? (xb + (size_t)row * (8 * 34 * 64)) : zrow;
    }

    v4i acc[4][4];
#pragma unroll
    for (int i = 0; i < 4; ++i)
#pragma unroll
        for (int j = 0; j < 4; ++j) acc[i][j] = (v4i){0, 0, 0, 0};

    const v4i* pwv = (const v4i*)wq + (co0 + m) * 4 + quad;

#pragma unroll
    for (int kh = 0; kh < 3; ++kh)
#pragma unroll
        for (int kw = 0; kw < 3; ++kw) {
            int tap = kh * 3 + kw;
#pragma unroll
            for (int cc = 0; cc < 2; ++cc) {
                int ci = kv * 2 + cc;        // channel chunk 0..7
                v4i a[4];
#pragma unroll
                for (int mt = 0; mt < 4; ++mt)
                    a[mt] = *((const v4i*)rp[kh + (mt >> 1)] +
                              (ci * 34 + m + (mt & 1) * 16 + kw) * 4 + quad);
#pragma unroll
                for (int nt = 0; nt < 4; ++nt) {
                    v4i bf = pwv[tap * 4096 + ci * 512 + nt * 64];
#pragma unroll
                    for (int mt = 0; mt < 4; ++mt)
                        acc[mt][nt] = __builtin_amdgcn_mfma_i32_16x16x64_i8(a[mt], bf, acc[mt][nt], 0, 0, 0);
                }
            }
        }

    // 2-round LDS tree combine of the 4 K-quarters
    if (kv >= 2) {
#pragma unroll
        for (int mt = 0; mt < 4; ++mt)
#pragma unroll
            for (int nt = 0; nt < 4; ++nt)
                red[kv - 2][(mt * 4 + nt) * 64 + lane] = acc[mt][nt];
    }
    __syncthreads();
    if (kv < 2) {
#pragma unroll
        for (int mt = 0; mt < 4; ++mt)
#pragma unroll
            for (int nt = 0; nt < 4; ++nt) {
                v4i p = red[kv][(mt * 4 + nt) * 64 + lane];
                acc[mt][nt].x += p.x; acc[mt][nt].y += p.y;
                acc[mt][nt].z += p.z; acc[mt][nt].w += p.w;
            }
    }
    __syncthreads();
    if (kv == 1) {
#pragma unroll
        for (int mt = 0; mt < 4; ++mt)
#pragma unroll
            for (int nt = 0; nt < 4; ++nt)
                red[0][(mt * 4 + nt) * 64 + lane] = acc[mt][nt];
    }
    __syncthreads();
    if (kv == 0) {
#pragma unroll
        for (int mt = 0; mt < 4; ++mt)
#pragma unroll
            for (int nt = 0; nt < 4; ++nt) {
                v4i p = red[0][(mt * 4 + nt) * 64 + lane];
                acc[mt][nt].x += p.x; acc[mt][nt].y += p.y;
                acc[mt][nt].z += p.z; acc[mt][nt].w += p.w;
            }

        // epilogue: C layout col(lane&15)=co-within-ntile, row(quad*4+reg)=w
        float s_act = __uint_as_float(amax[0]) / 127.0f;
        float mx = 0.f;
#pragma unroll
        for (int nt = 0; nt < 4; ++nt) {
            int co = co0 + nt * 16 + m;
            float sf = s_act * wsc[co];
#pragma unroll
            for (int mt = 0; mt < 4; ++mt) {
                int row = h0 + (mt >> 1);
                float* yb = y + ((size_t)(bb * 128 + co)) * 1024 + row * 32 + (mt & 1) * 16;
                float4 vv;
                vv.x = (float)acc[mt][nt][0] * sf;
                vv.y = (float)acc[mt][nt][1] * sf;
                vv.z = (float)acc[mt][nt][2] * sf;
                vv.w = (float)acc[mt][nt][3] * sf;
                *(float4*)(yb + quad * 4) = vv;
                mx = fmaxf(mx, fmaxf(fmaxf(fabsf(vv.x), fabsf(vv.y)),
                                     fmaxf(fabsf(vv.z), fabsf(vv.w))));
            }
        }
        mx = wave_max(mx);
        if (lane == 0) atomicMax(amaxy, __float_as_uint(mx));
    }
}

// ---- kernel 5: final requant in place + write s_out -----------------------
// keeps true f32 division (matches ref rounding at the final stage)
__global__ __launch_bounds__(256) void k_yquant(float* __restrict__ yout,
                                                const unsigned* __restrict__ ws_u) {
    float s_out = __uint_as_float(ws_u[1]) / 127.0f;
    float4* y4 = (float4*)yout;
    int stride = gridDim.x * blockDim.x;
    for (int i = blockIdx.x * blockDim.x + threadIdx.x; i < 1048576; i += stride) {
        float4 v = y4[i];
        v.x = fminf(fmaxf(rintf(v.x / s_out), -128.f), 127.f) * s_out;
        v.y = fminf(fmaxf(rintf(v.y / s_out), -128.f), 127.f) * s_out;
        v.z = fminf(fmaxf(rintf(v.z / s_out), -128.f), 127.f) * s_out;
        v.w = fminf(fmaxf(rintf(v.w / s_out), -128.f), 127.f) * s_out;
        y4[i] = v;
    }
    if (blockIdx.x == 0 && threadIdx.x == 0) yout[4194304] = s_out;
}

extern "C" void kernel_launch(void* const* d_in, const int* in_sizes, int n_in,
                              void* d_out, int out_size, void* d_ws, size_t ws_size,
                              hipStream_t stream) {
    const float* x     = (const float*)d_in[0];
    const float* asf   = (const float*)d_in[1];
    const float* gamma = (const float*)d_in[2];
    const float* beta  = (const float*)d_in[3];
    const float* mean  = (const float*)d_in[4];
    const float* var   = (const float*)d_in[5];
    const float* cw    = (const float*)d_in[6];

    float*    ws_f = (float*)d_ws;
    unsigned* ws_u = (unsigned*)d_ws;
    signed char*   wq   = (signed char*)d_ws + WS_WQ;
    unsigned char* x2   = (unsigned char*)d_ws + WS_X2;
    unsigned char* zrow = (unsigned char*)d_ws + WS_ZROW;
    float* y = (float*)d_out;

    k_prep<<<129, 512, 0, stream>>>(gamma, beta, mean, var, asf, cw,
                                    ws_f, ws_u, ws_f + WS_WSC / 4, wq);
    k_xmax<<<1024, 256, 0, stream>>>((const float4*)x, ws_f, ws_u);
    k_xquant<<<1024, 256, 0, stream>>>((const float4*)x, ws_f, ws_u,
                                       (unsigned*)x2, (unsigned*)zrow);
    k_conv<<<1024, 256, 0, stream>>>(x2, zrow, wq, ws_f + WS_WSC / 4,
                                     ws_u, ws_u + 1, y);
    k_yquant<<<1024, 256, 0, stream>>>(y, ws_u);
}

// Round 5
// 176.455 us; speedup vs baseline: 1.4771x; 1.0466x over previous
//
#include <hip/hip_runtime.h>

// ---------------------------------------------------------------------------
// Q_DenseLayer: BN-fold int8 affine -> ReLU -> per-tensor 8b quant ->
// int8 3x3 conv (MFMA i32_16x16x64_i8) -> per-tensor 8b requant.
// Shapes: x[32,512,32,32] f32, W[128,512,3,3] f32, out y[32,128,32,32] + s_out.
//
// R5: k_conv at 3 blocks/CU (launch_bounds(256,3), 168-reg budget, fits
// 144-reg need -> no spill) + single-barrier 48KB LDS reduction.
// k_xmax dispatch eliminated: per-channel x min/max in k_prep (1 block/ch,
// race-free), s_act derived in k_xquant (exact: fma monotone in x).
// wq stores coalesced (tap-outer loop -> 64B lines).
// ---------------------------------------------------------------------------

typedef int v4i __attribute__((ext_vector_type(4)));

// workspace byte offsets
#define WS_A1    64        // 512 floats: A1_c = w_int*bn_sf/s_in
#define WS_B1    2176      // 512 floats: B1_c = b_int*bn_sf
#define WS_WSC   4224      // 128 floats
#define WS_XMX   4736      // 512 floats: per-channel max(x)
#define WS_XMN   6784      // 512 floats: per-channel min(x)
#define WS_WQ    12288     // 589824 int8, layout [tap][cc(8)][co(128)][c64]
#define WS_X2    602112    // 17825792 uint8: [b][h(32)][cc(8)][w'(34)][c64]
#define WS_ZROW  18427904  // 17408 uint8 zero row (8*34*64)
// ws_f[3] = s_act (written by k_xquant block 0), ws_u[1] = absmax(y) bits

__device__ __forceinline__ float wave_max(float m) {
#pragma unroll
    for (int off = 32; off; off >>= 1) m = fmaxf(m, __shfl_xor(m, off));
    return m;
}

// ---- kernel 1: fused prep ---------------------------------------------------
// blocks 0..127: conv-weight quant (coalesced wq stores)
// block 128:     BN fold -> A1/B1
// blocks 129..640: per-channel x max/min (block c-129 owns channel c)
__global__ __launch_bounds__(512) void k_prep(
    const float* __restrict__ gamma, const float* __restrict__ beta,
    const float* __restrict__ mean,  const float* __restrict__ var,
    const float* __restrict__ asf,   const float* __restrict__ cw,
    const float4* __restrict__ x4,
    float* ws_f, unsigned* ws_u, float* __restrict__ wsc,
    signed char* __restrict__ wq) {
    int t = threadIdx.x;
    int bid = blockIdx.x;
    __shared__ float red[16];
    if (bid < 128) {
        int co = bid;
        const float* w = cw + (size_t)co * 4608;
        float m = 0.f;
        for (int j = t; j < 4608; j += 512) m = fmaxf(m, fabsf(w[j]));
        m = wave_max(m);
        if ((t & 63) == 0) red[t >> 6] = m;
        __syncthreads();
        float mall = red[0];
#pragma unroll
        for (int i = 1; i < 8; ++i) mall = fmaxf(mall, red[i]);
        float sc = mall / 127.0f;
        if (t == 0) wsc[co] = sc;
        // tap-outer: 64-lane groups write contiguous 64B lines of wq
#pragma unroll
        for (int tap = 0; tap < 9; ++tap) {
            float q = fminf(fmaxf(rintf(w[t * 9 + tap] / sc), -128.f), 127.f);
            wq[(((size_t)(tap * 8 + (t >> 6)) * 128 + co) * 64) + (t & 63)] = (signed char)q;
        }
    } else if (bid == 128) {
        float wbn = gamma[t] / sqrtf(var[t] + 1e-5f);
        float bbn = beta[t] - mean[t] * wbn;
        float m = wave_max(fabsf(wbn));
        if ((t & 63) == 0) red[t >> 6] = m;
        __syncthreads();
        float mall = red[0];
#pragma unroll
        for (int i = 1; i < 8; ++i) mall = fmaxf(mall, red[i]);
        float ws_bn = mall / 127.0f;
        float s_in  = asf[0];
        float bn_sf = ws_bn * s_in;
        float wint  = fminf(fmaxf(rintf(wbn / ws_bn), -128.f), 127.f);
        float bint  = rintf(bbn / bn_sf);
        ws_f[WS_A1 / 4 + t] = wint * bn_sf / s_in;  // x1 = fmaf(x, A1, B1)
        ws_f[WS_B1 / 4 + t] = bint * bn_sf;
        if (t == 0) ws_u[1] = 0u;  // absmax(y) bits
    } else {
        // per-channel stats: block owns channel c, scans 32 (b,c) planes
        int c = bid - 129;
        float mx = -3.4e38f, mn = 3.4e38f;
#pragma unroll
        for (int r = 0; r < 16; ++r) {
            int bbb = r * 2 + (t >> 8);
            float4 v = x4[((size_t)(bbb * 512 + c)) * 256 + (t & 255)];
            mx = fmaxf(mx, fmaxf(fmaxf(v.x, v.y), fmaxf(v.z, v.w)));
            mn = fminf(mn, fminf(fminf(v.x, v.y), fminf(v.z, v.w)));
        }
        mx = wave_max(mx);
        mn = -wave_max(-mn);
        if ((t & 63) == 0) { red[t >> 6] = mx; red[8 + (t >> 6)] = mn; }
        __syncthreads();
        if (t == 0) {
            float M = red[0], N = red[8];
#pragma unroll
            for (int i = 1; i < 8; ++i) { M = fmaxf(M, red[i]); N = fminf(N, red[8 + i]); }
            ws_f[WS_XMX / 4 + c] = M;
            ws_f[WS_XMN / 4 + c] = N;
        }
    }
}

// ---- kernel 2: quantize x to int8 chunk-major halo layout ------------------
// derives s_act from per-channel stats (exact), then quantize + transpose.
__global__ __launch_bounds__(256) void k_xquant(
    const float4* __restrict__ x4, float* __restrict__ ws_f,
    unsigned* __restrict__ x2u, unsigned* __restrict__ zrowu) {
    int bb = blockIdx.x >> 5, h = blockIdx.x & 31;
    const float* A1 = ws_f + WS_A1 / 4;
    const float* B1 = ws_f + WS_B1 / 4;
    const float* XMX = ws_f + WS_XMX / 4;
    const float* XMN = ws_f + WS_XMN / 4;
    int t = threadIdx.x;

    // s_act = max_c relu(max(fmaf(Mx,A,B), fmaf(mn,A,B))) / 127  (== global max)
    __shared__ float sred[4];
    float cand = 0.f;
#pragma unroll
    for (int c0 = 0; c0 < 512; c0 += 256) {
        int c = c0 + t;
        float A = A1[c], B = B1[c];
        cand = fmaxf(cand, fmaxf(fmaf(XMX[c], A, B), fmaf(XMN[c], A, B)));
    }
    cand = wave_max(cand);
    if ((t & 63) == 0) sred[t >> 6] = cand;
    __syncthreads();
    float xm = fmaxf(fmaxf(sred[0], sred[1]), fmaxf(sred[2], sred[3]));
    float inv_sact = 127.0f / xm;
    if (blockIdx.x == 0 && t == 0) ws_f[3] = xm / 127.0f;  // s_act for k_conv

    // zero halo columns w'=0 and w'=33 for this (bb,h): 8cc x 2 x 64B
    {
        int cc = t >> 5, rem = t & 31;
        int wp = (rem >> 4) * 33, inner = rem & 15;
        x2u[((size_t)(((bb * 32 + h) * 8 + cc) * 34 + wp)) * 16 + inner] = 0u;
    }
    // zero the shared zero-row (17408 B) using blocks 0..16
    if (blockIdx.x < 17) {
        int idx = blockIdx.x * 256 + t;
        if (idx < 4352) zrowu[idx] = 0u;
    }

    __shared__ unsigned lds[512 * 9];  // row stride 9 dwords (8 data + 1 pad)

#pragma unroll
    for (int it = 0; it < 16; ++it) {
        int idx = it * 256 + t;
        int c = idx >> 3, f4 = idx & 7;
        float4 v = x4[((size_t)bb * 512 + c) * 256 + h * 8 + f4];
        float A = A1[c] * inv_sact, B = B1[c] * inv_sact;
        unsigned q0 = (unsigned)(int)fminf(rintf(fmaxf(fmaf(v.x, A, B), 0.f)), 127.f);
        unsigned q1 = (unsigned)(int)fminf(rintf(fmaxf(fmaf(v.y, A, B), 0.f)), 127.f);
        unsigned q2 = (unsigned)(int)fminf(rintf(fmaxf(fmaf(v.z, A, B), 0.f)), 127.f);
        unsigned q3 = (unsigned)(int)fminf(rintf(fmaxf(fmaf(v.w, A, B), 0.f)), 127.f);
        lds[c * 9 + f4] = q0 | (q1 << 8) | (q2 << 16) | (q3 << 24);
    }
    __syncthreads();

    // phase 2: gather 4 channel-dwords, 4x4 byte transpose, write chunk-major
#pragma unroll
    for (int it2 = 0; it2 < 4; ++it2) {
        int cdw = (t & 31) + ((t >> 6) << 5);          // channel dword 0..127
        int wq4 = ((t >> 5) & 1) + (it2 << 1);         // 0..7
        unsigned u0 = lds[(4 * cdw + 0) * 9 + wq4];
        unsigned u1 = lds[(4 * cdw + 1) * 9 + wq4];
        unsigned u2 = lds[(4 * cdw + 2) * 9 + wq4];
        unsigned u3 = lds[(4 * cdw + 3) * 9 + wq4];
        int cc = cdw >> 4, inner = cdw & 15;
        unsigned* dst = x2u + ((size_t)(((bb * 32 + h) * 8 + cc) * 34 + wq4 * 4 + 1)) * 16 + inner;
#pragma unroll
        for (int k = 0; k < 4; ++k) {
            unsigned o = ((u0 >> (8 * k)) & 255) | (((u1 >> (8 * k)) & 255) << 8) |
                         (((u2 >> (8 * k)) & 255) << 16) | (((u3 >> (8 * k)) & 255) << 24);
            dst[(size_t)k * 16] = o;
        }
    }
}

// ---- kernel 3: int8 3x3 conv via MFMA -------------------------------------
// block = one tile (64px = rows h0,h0+1; 64co) x 4 K-quarter waves.
// launch_bounds(256,3): 168-reg budget (need ~144, no spill), 12 waves/CU.
__global__ __launch_bounds__(256, 3) void k_conv(
    const unsigned char* __restrict__ x2, const unsigned char* __restrict__ zrow,
    const signed char* __restrict__ wq,
    const float* __restrict__ wsc, const float* __restrict__ ws_f,
    unsigned* __restrict__ amaxy, float* __restrict__ y) {
    __shared__ v4i red[3][1024];  // 48 KB: kv=1,2,3 partial tiles
    int t = threadIdx.x;
    int lane = t & 63, kv = t >> 6;          // kv = K quarter 0..3
    int m = lane & 15, quad = lane >> 4;

    int bid = blockIdx.x;
    int tile = (bid & 7) * 128 + (bid >> 3); // XCD swizzle: 128 tiles per XCD
    int ch = tile & 1;                       // co half
    int rowpair = (tile >> 1) & 15;
    int bb = tile >> 5;
    int h0 = rowpair * 2;
    int co0 = ch * 64;

    const unsigned char* xb = x2 + (size_t)bb * (32 * 8 * 34 * 64);
    const unsigned char* rp[4];
#pragma unroll
    for (int j = 0; j < 4; ++j) {
        int row = h0 - 1 + j;
        rp[j] = ((unsigned)row < 32u) ? (xb + (size_t)row * (8 * 34 * 64)) : zrow;
    }

    v4i acc[4][4];
#pragma unroll
    for (int i = 0; i < 4; ++i)
#pragma unroll
        for (int j = 0; j < 4; ++j) acc[i][j] = (v4i){0, 0, 0, 0};

    const v4i* pwv = (const v4i*)wq + (co0 + m) * 4 + quad;

#pragma unroll
    for (int kh = 0; kh < 3; ++kh)
#pragma unroll
        for (int kw = 0; kw < 3; ++kw) {
            int tap = kh * 3 + kw;
#pragma unroll
            for (int cc = 0; cc < 2; ++cc) {
                int ci = kv * 2 + cc;        // channel chunk 0..7
                v4i a[4];
#pragma unroll
                for (int mt = 0; mt < 4; ++mt)
                    a[mt] = *((const v4i*)rp[kh + (mt >> 1)] +
                              (ci * 34 + m + (mt & 1) * 16 + kw) * 4 + quad);
#pragma unroll
                for (int nt = 0; nt < 4; ++nt) {
                    v4i bf = pwv[tap * 4096 + ci * 512 + nt * 64];
#pragma unroll
                    for (int mt = 0; mt < 4; ++mt)
                        acc[mt][nt] = __builtin_amdgcn_mfma_i32_16x16x64_i8(a[mt], bf, acc[mt][nt], 0, 0, 0);
                }
            }
        }

    // single-barrier combine of the 4 K-quarters
    if (kv > 0) {
#pragma unroll
        for (int mt = 0; mt < 4; ++mt)
#pragma unroll
            for (int nt = 0; nt < 4; ++nt)
                red[kv - 1][(mt * 4 + nt) * 64 + lane] = acc[mt][nt];
    }
    __syncthreads();
    if (kv == 0) {
#pragma unroll
        for (int r = 0; r < 3; ++r)
#pragma unroll
            for (int mt = 0; mt < 4; ++mt)
#pragma unroll
                for (int nt = 0; nt < 4; ++nt) {
                    v4i p = red[r][(mt * 4 + nt) * 64 + lane];
                    acc[mt][nt].x += p.x; acc[mt][nt].y += p.y;
                    acc[mt][nt].z += p.z; acc[mt][nt].w += p.w;
                }

        // epilogue: C layout col(lane&15)=co-within-ntile, row(quad*4+reg)=w
        float s_act = ws_f[3];
        float mx = 0.f;
#pragma unroll
        for (int nt = 0; nt < 4; ++nt) {
            int co = co0 + nt * 16 + m;
            float sf = s_act * wsc[co];
#pragma unroll
            for (int mt = 0; mt < 4; ++mt) {
                int row = h0 + (mt >> 1);
                float* yb = y + ((size_t)(bb * 128 + co)) * 1024 + row * 32 + (mt & 1) * 16;
                float4 vv;
                vv.x = (float)acc[mt][nt][0] * sf;
                vv.y = (float)acc[mt][nt][1] * sf;
                vv.z = (float)acc[mt][nt][2] * sf;
                vv.w = (float)acc[mt][nt][3] * sf;
                *(float4*)(yb + quad * 4) = vv;
                mx = fmaxf(mx, fmaxf(fmaxf(fabsf(vv.x), fabsf(vv.y)),
                                     fmaxf(fabsf(vv.z), fabsf(vv.w))));
            }
        }
        mx = wave_max(mx);
        if (lane == 0) atomicMax(amaxy, __float_as_uint(mx));
    }
}

// ---- kernel 4: final requant in place + write s_out -----------------------
__global__ __launch_bounds__(256) void k_yquant(float* __restrict__ yout,
                                                const unsigned* __restrict__ ws_u) {
    float s_out = __uint_as_float(ws_u[1]) / 127.0f;
    float4* y4 = (float4*)yout;
    int stride = gridDim.x * blockDim.x;
    for (int i = blockIdx.x * blockDim.x + threadIdx.x; i < 1048576; i += stride) {
        float4 v = y4[i];
        v.x = fminf(fmaxf(rintf(v.x / s_out), -128.f), 127.f) * s_out;
        v.y = fminf(fmaxf(rintf(v.y / s_out), -128.f), 127.f) * s_out;
        v.z = fminf(fmaxf(rintf(v.z / s_out), -128.f), 127.f) * s_out;
        v.w = fminf(fmaxf(rintf(v.w / s_out), -128.f), 127.f) * s_out;
        y4[i] = v;
    }
    if (blockIdx.x == 0 && threadIdx.x == 0) yout[4194304] = s_out;
}

extern "C" void kernel_launch(void* const* d_in, const int* in_sizes, int n_in,
                              void* d_out, int out_size, void* d_ws, size_t ws_size,
                              hipStream_t stream) {
    const float* x     = (const float*)d_in[0];
    const float* asf   = (const float*)d_in[1];
    const float* gamma = (const float*)d_in[2];
    const float* beta  = (const float*)d_in[3];
    const float* mean  = (const float*)d_in[4];
    const float* var   = (const float*)d_in[5];
    const float* cw    = (const float*)d_in[6];

    float*    ws_f = (float*)d_ws;
    unsigned* ws_u = (unsigned*)d_ws;
    signed char*   wq   = (signed char*)d_ws + WS_WQ;
    unsigned char* x2   = (unsigned char*)d_ws + WS_X2;
    unsigned char* zrow = (unsigned char*)d_ws + WS_ZROW;
    float* y = (float*)d_out;

    k_prep<<<641, 512, 0, stream>>>(gamma, beta, mean, var, asf, cw,
                                    (const float4*)x, ws_f, ws_u,
                                    ws_f + WS_WSC / 4, wq);
    k_xquant<<<1024, 256, 0, stream>>>((const float4*)x, ws_f,
                                       (unsigned*)x2, (unsigned*)zrow);
    k_conv<<<1024, 256, 0, stream>>>(x2, zrow, wq, ws_f + WS_WSC / 4,
                                     ws_f, ws_u + 1, y);
    k_yquant<<<1024, 256, 0, stream>>>(y, ws_u);
}

// Round 6
// 166.609 us; speedup vs baseline: 1.5644x; 1.0591x over previous
//
#include <hip/hip_runtime.h>

// ---------------------------------------------------------------------------
// Q_DenseLayer: BN-fold int8 affine -> ReLU -> per-tensor 8b quant ->
// int8 3x3 conv (MFMA i32_16x16x64_i8) -> per-tensor 8b requant.
// Shapes: x[32,512,32,32] f32, W[128,512,3,3] f32, out y[32,128,32,32] + s_out.
//
// R6: de-permute fragment loads. MFMA lane = m + 16*quad, so layouts now put
// the quad index as a memory dimension:
//   x2: [b][h][ci8][cq4][w'34][16B]  -> A idx = ci*136 + quad*34 + w
//   wq: [tap][ci][cq4][co128][16B]   -> B idx = (tap*8+ci)*512 + quad*128 + co
// Each quarter-wave now reads 256B contiguous (16 granules/wave vs ~64 before).
// k_conv: R4 2-stage tree (32KB LDS) + launch_bounds(256,3) (170-reg budget,
// ~144 need, no spill). x-stats 1024-way w/ encoded-uint atomicMax.
// ---------------------------------------------------------------------------

typedef int v4i __attribute__((ext_vector_type(4)));

// workspace byte offsets (total 18,441,792 <= proven 18,445,312)
#define WS_A1    64        // 512 f: A1_c = w_int*bn_sf/s_in
#define WS_B1    2112      // 512 f: B1_c = b_int*bn_sf
#define WS_WSC   4160      // 128 f
#define WS_XMX   4672      // 512 u32: enc(max x_c)   (memset 0 = -inf identity)
#define WS_XMN   6720      // 512 u32: enc(max -x_c)
#define WS_WQ    8768      // 589824 i8: [tap][ci][cq][co][16]
#define WS_X2    598592    // 17825792 u8: [b][h][ci][cq][w'34][16]
#define WS_ZROW  18424384  // 17408 u8 zero row
// ws_f[3] = s_act (k_xquant blk0), ws_u[1] = absmax(y) bits

__device__ __forceinline__ float wave_max(float m) {
#pragma unroll
    for (int off = 32; off; off >>= 1) m = fmaxf(m, __shfl_xor(m, off));
    return m;
}
// order-preserving float<->uint for atomicMax (memset-0 == identity)
__device__ __forceinline__ unsigned fenc(float f) {
    unsigned u = __float_as_uint(f);
    return ((int)u < 0) ? ~u : (u | 0x80000000u);
}
__device__ __forceinline__ float fdec(unsigned k) {
    return __uint_as_float((k & 0x80000000u) ? (k & 0x7fffffffu) : ~k);
}

// ---- kernel 1: fused prep ---------------------------------------------------
// blocks 0..127: conv-weight quant -> new wq layout
// block 128:     BN fold -> A1/B1
// blocks 129..1152: per-channel x max / max(-x), 2 blocks per channel
__global__ __launch_bounds__(512) void k_prep(
    const float* __restrict__ gamma, const float* __restrict__ beta,
    const float* __restrict__ mean,  const float* __restrict__ var,
    const float* __restrict__ asf,   const float* __restrict__ cw,
    const float4* __restrict__ x4,
    float* ws_f, unsigned* ws_u, float* __restrict__ wsc,
    signed char* __restrict__ wq) {
    int t = threadIdx.x;
    int bid = blockIdx.x;
    __shared__ float red[16];
    if (bid < 128) {
        int co = bid;
        const float* w = cw + (size_t)co * 4608;
        float m = 0.f;
        for (int j = t; j < 4608; j += 512) m = fmaxf(m, fabsf(w[j]));
        m = wave_max(m);
        if ((t & 63) == 0) red[t >> 6] = m;
        __syncthreads();
        float mall = red[0];
#pragma unroll
        for (int i = 1; i < 8; ++i) mall = fmaxf(mall, red[i]);
        float sc = mall / 127.0f;
        if (t == 0) wsc[co] = sc;
        int ci = t >> 6, cq = (t >> 4) & 3, cb = t & 15;
#pragma unroll
        for (int tap = 0; tap < 9; ++tap) {
            float q = fminf(fmaxf(rintf(w[t * 9 + tap] / sc), -128.f), 127.f);
            wq[(((size_t)(tap * 8 + ci) * 4 + cq) * 128 + co) * 16 + cb] = (signed char)q;
        }
    } else if (bid == 128) {
        float wbn = gamma[t] / sqrtf(var[t] + 1e-5f);
        float bbn = beta[t] - mean[t] * wbn;
        float m = wave_max(fabsf(wbn));
        if ((t & 63) == 0) red[t >> 6] = m;
        __syncthreads();
        float mall = red[0];
#pragma unroll
        for (int i = 1; i < 8; ++i) mall = fmaxf(mall, red[i]);
        float ws_bn = mall / 127.0f;
        float s_in  = asf[0];
        float bn_sf = ws_bn * s_in;
        float wint  = fminf(fmaxf(rintf(wbn / ws_bn), -128.f), 127.f);
        float bint  = rintf(bbn / bn_sf);
        ws_f[WS_A1 / 4 + t] = wint * bn_sf / s_in;  // x1 = fmaf(x, A1, B1)
        ws_f[WS_B1 / 4 + t] = bint * bn_sf;
        if (t == 0) ws_u[1] = 0u;  // absmax(y) bits
    } else {
        // 2 blocks per channel: block scans 16 of 32 images
        int idx = bid - 129;
        int c = idx >> 1, half = idx & 1;
        float mx = -3.4e38f, mn = 3.4e38f;
#pragma unroll
        for (int r = 0; r < 8; ++r) {
            int bbb = half * 16 + r * 2 + (t >> 8);
            float4 v = x4[((size_t)(bbb * 512 + c)) * 256 + (t & 255)];
            mx = fmaxf(mx, fmaxf(fmaxf(v.x, v.y), fmaxf(v.z, v.w)));
            mn = fminf(mn, fminf(fminf(v.x, v.y), fminf(v.z, v.w)));
        }
        mx = wave_max(mx);
        mn = -wave_max(-mn);
        if ((t & 63) == 0) { red[t >> 6] = mx; red[8 + (t >> 6)] = mn; }
        __syncthreads();
        if (t == 0) {
            float M = red[0], N = red[8];
#pragma unroll
            for (int i = 1; i < 8; ++i) { M = fmaxf(M, red[i]); N = fminf(N, red[8 + i]); }
            atomicMax(ws_u + WS_XMX / 4 + c, fenc(M));
            atomicMax(ws_u + WS_XMN / 4 + c, fenc(-N));
        }
    }
}

// ---- kernel 2: quantize x to int8 [ci][cq][w'][16] halo layout -------------
__global__ __launch_bounds__(256) void k_xquant(
    const float4* __restrict__ x4, float* __restrict__ ws_f,
    const unsigned* __restrict__ ws_u,
    unsigned* __restrict__ x2u, unsigned* __restrict__ zrowu) {
    int bb = blockIdx.x >> 5, h = blockIdx.x & 31;
    const float* A1 = ws_f + WS_A1 / 4;
    const float* B1 = ws_f + WS_B1 / 4;
    const unsigned* XMX = ws_u + WS_XMX / 4;
    const unsigned* XMN = ws_u + WS_XMN / 4;
    int t = threadIdx.x;

    // s_act from per-channel stats (exact: fma monotone in x, relu clamp >=0)
    __shared__ float sred[4];
    float cand = 0.f;
#pragma unroll
    for (int c0 = 0; c0 < 512; c0 += 256) {
        int c = c0 + t;
        float A = A1[c], B = B1[c];
        float mx = fdec(XMX[c]), mn = -fdec(XMN[c]);
        cand = fmaxf(cand, fmaxf(fmaf(mx, A, B), fmaf(mn, A, B)));
    }
    cand = wave_max(cand);
    if ((t & 63) == 0) sred[t >> 6] = cand;
    __syncthreads();
    float xm = fmaxf(fmaxf(sred[0], sred[1]), fmaxf(sred[2], sred[3]));
    float inv_sact = 127.0f / xm;
    if (blockIdx.x == 0 && t == 0) ws_f[3] = xm / 127.0f;  // s_act for k_conv

    size_t rowd = (size_t)(bb * 32 + h) * 4352;  // dwords per (b,h) row
    // zero halo columns w'=0,33: 32 (ci,cq) x 2 sides x 4 dwords
    {
        int p = t >> 3, side = (t >> 2) & 1, d = t & 3;
        x2u[rowd + (p * 34 + side * 33) * 4 + d] = 0u;
    }
    // zero shared zero-row (17408 B) with blocks 0..16
    if (blockIdx.x < 17) {
        int idx = blockIdx.x * 256 + t;
        if (idx < 4352) zrowu[idx] = 0u;
    }

    __shared__ unsigned lds[512 * 9];  // [c][w4(8)] packed bytes, +1 pad

#pragma unroll
    for (int it = 0; it < 16; ++it) {
        int idx = it * 256 + t;
        int c = idx >> 3, f4 = idx & 7;
        float4 v = x4[((size_t)bb * 512 + c) * 256 + h * 8 + f4];
        float A = A1[c] * inv_sact, B = B1[c] * inv_sact;
        unsigned q0 = (unsigned)(int)fminf(rintf(fmaxf(fmaf(v.x, A, B), 0.f)), 127.f);
        unsigned q1 = (unsigned)(int)fminf(rintf(fmaxf(fmaf(v.y, A, B), 0.f)), 127.f);
        unsigned q2 = (unsigned)(int)fminf(rintf(fmaxf(fmaf(v.z, A, B), 0.f)), 127.f);
        unsigned q3 = (unsigned)(int)fminf(rintf(fmaxf(fmaf(v.w, A, B), 0.f)), 127.f);
        lds[c * 9 + f4] = q0 | (q1 << 8) | (q2 << 16) | (q3 << 24);
    }
    __syncthreads();

    // phase 2: byte-transpose into [ci][cq][w'][16B]; half-wave-contiguous
    // uint4 stores. thread = (p-lo, s, k): p=(ci,cq), s=w4 group, k=w within 4
#pragma unroll
    for (int it = 0; it < 4; ++it) {
        int p = it * 8 + (t >> 5);   // 0..31 = ci*4+cq
        int s = (t >> 2) & 7;        // w4 group
        int k = t & 3;               // w = s*4+k, w' = w+1
        unsigned L[16];
#pragma unroll
        for (int j = 0; j < 16; ++j) L[j] = lds[(p * 16 + j) * 9 + s];
        uint4 o;
        unsigned* op = (unsigned*)&o;
#pragma unroll
        for (int d = 0; d < 4; ++d)
            op[d] = ((L[4 * d] >> (8 * k)) & 255u) |
                    (((L[4 * d + 1] >> (8 * k)) & 255u) << 8) |
                    (((L[4 * d + 2] >> (8 * k)) & 255u) << 16) |
                    (((L[4 * d + 3] >> (8 * k)) & 255u) << 24);
        *(uint4*)(x2u + rowd + (size_t)(p * 34 + s * 4 + 1 + k) * 4) = o;
    }
}

// ---- kernel 3: int8 3x3 conv via MFMA -------------------------------------
// block = tile (64px = rows h0,h0+1; 64co) x 4 K-quarter waves; 2-stage tree.
// All fragment loads quarter-wave-contiguous in the new layouts.
__global__ __launch_bounds__(256, 3) void k_conv(
    const unsigned char* __restrict__ x2, const unsigned char* __restrict__ zrow,
    const signed char* __restrict__ wq,
    const float* __restrict__ wsc, const float* __restrict__ ws_f,
    unsigned* __restrict__ amaxy, float* __restrict__ y) {
    __shared__ v4i red[2][1024];  // 32 KB
    int t = threadIdx.x;
    int lane = t & 63, kv = t >> 6;          // kv = K quarter 0..3
    int m = lane & 15, quad = lane >> 4;

    int bid = blockIdx.x;
    int tile = (bid & 7) * 128 + (bid >> 3); // XCD swizzle
    int ch = tile & 1;
    int rowpair = (tile >> 1) & 15;
    int bb = tile >> 5;
    int h0 = rowpair * 2;
    int co0 = ch * 64;

    const unsigned char* xb = x2 + (size_t)bb * (32 * 17408);
    const v4i* rp[4];
#pragma unroll
    for (int j = 0; j < 4; ++j) {
        int row = h0 - 1 + j;
        rp[j] = (const v4i*)(((unsigned)row < 32u) ? (xb + (size_t)row * 17408) : zrow);
    }

    v4i acc[4][4];
#pragma unroll
    for (int i = 0; i < 4; ++i)
#pragma unroll
        for (int j = 0; j < 4; ++j) acc[i][j] = (v4i){0, 0, 0, 0};

    const v4i* pw = (const v4i*)wq + quad * 128 + co0 + m;
    int abase = quad * 34 + m;

#pragma unroll
    for (int kh = 0; kh < 3; ++kh)
#pragma unroll
        for (int kw = 0; kw < 3; ++kw) {
            int tap = kh * 3 + kw;
#pragma unroll
            for (int cc = 0; cc < 2; ++cc) {
                int ci = kv * 2 + cc;
                v4i a[4];
#pragma unroll
                for (int mt = 0; mt < 4; ++mt)
                    a[mt] = rp[kh + (mt >> 1)][ci * 136 + abase + kw + (mt & 1) * 16];
#pragma unroll
                for (int nt = 0; nt < 4; ++nt) {
                    v4i bf = pw[(tap * 8 + ci) * 512 + nt * 16];
#pragma unroll
                    for (int mt = 0; mt < 4; ++mt)
                        acc[mt][nt] = __builtin_amdgcn_mfma_i32_16x16x64_i8(a[mt], bf, acc[mt][nt], 0, 0, 0);
                }
            }
        }

    // 2-stage tree combine of the 4 K-quarters
    if (kv >= 2) {
#pragma unroll
        for (int mt = 0; mt < 4; ++mt)
#pragma unroll
            for (int nt = 0; nt < 4; ++nt)
                red[kv - 2][(mt * 4 + nt) * 64 + lane] = acc[mt][nt];
    }
    __syncthreads();
    if (kv < 2) {
#pragma unroll
        for (int mt = 0; mt < 4; ++mt)
#pragma unroll
            for (int nt = 0; nt < 4; ++nt) {
                v4i p = red[kv][(mt * 4 + nt) * 64 + lane];
                acc[mt][nt].x += p.x; acc[mt][nt].y += p.y;
                acc[mt][nt].z += p.z; acc[mt][nt].w += p.w;
            }
    }
    __syncthreads();
    if (kv == 1) {
#pragma unroll
        for (int mt = 0; mt < 4; ++mt)
#pragma unroll
            for (int nt = 0; nt < 4; ++nt)
                red[0][(mt * 4 + nt) * 64 + lane] = acc[mt][nt];
    }
    __syncthreads();
    if (kv == 0) {
#pragma unroll
        for (int mt = 0; mt < 4; ++mt)
#pragma unroll
            for (int nt = 0; nt < 4; ++nt) {
                v4i p = red[0][(mt * 4 + nt) * 64 + lane];
                acc[mt][nt].x += p.x; acc[mt][nt].y += p.y;
                acc[mt][nt].z += p.z; acc[mt][nt].w += p.w;
            }

        // epilogue: C layout col(lane&15)=co, row(quad*4+reg)=w
        float s_act = ws_f[3];
        float mx = 0.f;
#pragma unroll
        for (int nt = 0; nt < 4; ++nt) {
            int co = co0 + nt * 16 + m;
            float sf = s_act * wsc[co];
#pragma unroll
            for (int mt = 0; mt < 4; ++mt) {
                int row = h0 + (mt >> 1);
                float* yb = y + ((size_t)(bb * 128 + co)) * 1024 + row * 32 + (mt & 1) * 16;
                float4 vv;
                vv.x = (float)acc[mt][nt][0] * sf;
                vv.y = (float)acc[mt][nt][1] * sf;
                vv.z = (float)acc[mt][nt][2] * sf;
                vv.w = (float)acc[mt][nt][3] * sf;
                *(float4*)(yb + quad * 4) = vv;
                mx = fmaxf(mx, fmaxf(fmaxf(fabsf(vv.x), fabsf(vv.y)),
                                     fmaxf(fabsf(vv.z), fabsf(vv.w))));
            }
        }
        mx = wave_max(mx);
        if (lane == 0) atomicMax(amaxy, __float_as_uint(mx));
    }
}

// ---- kernel 4: final requant in place + write s_out -----------------------
__global__ __launch_bounds__(256) void k_yquant(float* __restrict__ yout,
                                                const unsigned* __restrict__ ws_u) {
    float s_out = __uint_as_float(ws_u[1]) / 127.0f;
    float4* y4 = (float4*)yout;
    int stride = gridDim.x * blockDim.x;
    for (int i = blockIdx.x * blockDim.x + threadIdx.x; i < 1048576; i += stride) {
        float4 v = y4[i];
        v.x = fminf(fmaxf(rintf(v.x / s_out), -128.f), 127.f) * s_out;
        v.y = fminf(fmaxf(rintf(v.y / s_out), -128.f), 127.f) * s_out;
        v.z = fminf(fmaxf(rintf(v.z / s_out), -128.f), 127.f) * s_out;
        v.w = fminf(fmaxf(rintf(v.w / s_out), -128.f), 127.f) * s_out;
        y4[i] = v;
    }
    if (blockIdx.x == 0 && threadIdx.x == 0) yout[4194304] = s_out;
}

extern "C" void kernel_launch(void* const* d_in, const int* in_sizes, int n_in,
                              void* d_out, int out_size, void* d_ws, size_t ws_size,
                              hipStream_t stream) {
    const float* x     = (const float*)d_in[0];
    const float* asf   = (const float*)d_in[1];
    const float* gamma = (const float*)d_in[2];
    const float* beta  = (const float*)d_in[3];
    const float* mean  = (const float*)d_in[4];
    const float* var   = (const float*)d_in[5];
    const float* cw    = (const float*)d_in[6];

    float*    ws_f = (float*)d_ws;
    unsigned* ws_u = (unsigned*)d_ws;
    signed char*   wq   = (signed char*)d_ws + WS_WQ;
    unsigned char* x2   = (unsigned char*)d_ws + WS_X2;
    unsigned char* zrow = (unsigned char*)d_ws + WS_ZROW;
    float* y = (float*)d_out;

    // init encoded stats slots (0 == -inf under fenc ordering)
    hipMemsetAsync((char*)d_ws + WS_XMX, 0, 4096, stream);

    k_prep<<<1153, 512, 0, stream>>>(gamma, beta, mean, var, asf, cw,
                                     (const float4*)x, ws_f, ws_u,
                                     ws_f + WS_WSC / 4, wq);
    k_xquant<<<1024, 256, 0, stream>>>((const float4*)x, ws_f, ws_u,
                                       (unsigned*)x2, (unsigned*)zrow);
    k_conv<<<1024, 256, 0, stream>>>(x2, zrow, wq, ws_f + WS_WSC / 4,
                                     ws_f, ws_u + 1, y);
    k_yquant<<<1024, 256, 0, stream>>>(y, ws_u);
}

// Round 7
// 164.923 us; speedup vs baseline: 1.5804x; 1.0102x over previous
//
#include <hip/hip_runtime.h>

// ---------------------------------------------------------------------------
// Q_DenseLayer: BN-fold int8 affine -> ReLU -> per-tensor 8b quant ->
// int8 3x3 conv (MFMA i32_16x16x64_i8) -> per-tensor 8b requant.
// Shapes: x[32,512,32,32] f32, W[128,512,3,3] f32, out y[32,128,32,32] + s_out.
//
// R7: drop memset dispatch (1 block/channel plain-store stats);
// k_xquant processes b in reverse for L3 tail reuse of x (x=268MB vs L3=256MB,
// k_prep streamed it b-ascending); stats blocks first in k_prep.
// Layouts (R6): x2 [b][h][ci8][cq4][w'34][16B], wq [tap][ci][cq4][co128][16B]
// -> all conv fragment loads quarter-wave-contiguous (16 granules/wave).
// ---------------------------------------------------------------------------

typedef int v4i __attribute__((ext_vector_type(4)));

// workspace byte offsets
#define WS_A1    64        // 512 f: A1_c = w_int*bn_sf/s_in
#define WS_B1    2112      // 512 f: B1_c = b_int*bn_sf
#define WS_WSC   4160      // 128 f
#define WS_XMX   4672      // 512 f: per-channel max(x)
#define WS_XMN   6720      // 512 f: per-channel min(x)
#define WS_WQ    8768      // 589824 i8: [tap][ci][cq][co][16]
#define WS_X2    598592    // 17825792 u8: [b][h][ci][cq][w'34][16]
#define WS_ZROW  18424384  // 17408 u8 zero row
// ws_f[3] = s_act (k_xquant blk0), ws_u[1] = absmax(y) bits

__device__ __forceinline__ float wave_max(float m) {
#pragma unroll
    for (int off = 32; off; off >>= 1) m = fmaxf(m, __shfl_xor(m, off));
    return m;
}

// ---- kernel 1: fused prep ---------------------------------------------------
// blocks 0..511:   per-channel x max/min (block c owns channel c, plain store)
// blocks 512..639: conv-weight quant (co = bid-512)
// block 640:       BN fold -> A1/B1
__global__ __launch_bounds__(512) void k_prep(
    const float* __restrict__ gamma, const float* __restrict__ beta,
    const float* __restrict__ mean,  const float* __restrict__ var,
    const float* __restrict__ asf,   const float* __restrict__ cw,
    const float4* __restrict__ x4,
    float* ws_f, unsigned* ws_u, float* __restrict__ wsc,
    signed char* __restrict__ wq) {
    int t = threadIdx.x;
    int bid = blockIdx.x;
    __shared__ float red[16];
    if (bid < 512) {
        // per-channel stats: block owns channel c, scans 32 (b,c) planes
        int c = bid;
        float mx = -3.4e38f, mn = 3.4e38f;
#pragma unroll
        for (int r = 0; r < 16; ++r) {
            int bbb = r * 2 + (t >> 8);
            float4 v = x4[((size_t)(bbb * 512 + c)) * 256 + (t & 255)];
            mx = fmaxf(mx, fmaxf(fmaxf(v.x, v.y), fmaxf(v.z, v.w)));
            mn = fminf(mn, fminf(fminf(v.x, v.y), fminf(v.z, v.w)));
        }
        mx = wave_max(mx);
        mn = -wave_max(-mn);
        if ((t & 63) == 0) { red[t >> 6] = mx; red[8 + (t >> 6)] = mn; }
        __syncthreads();
        if (t == 0) {
            float M = red[0], N = red[8];
#pragma unroll
            for (int i = 1; i < 8; ++i) { M = fmaxf(M, red[i]); N = fminf(N, red[8 + i]); }
            ws_f[WS_XMX / 4 + c] = M;
            ws_f[WS_XMN / 4 + c] = N;
        }
    } else if (bid < 640) {
        int co = bid - 512;
        const float* w = cw + (size_t)co * 4608;
        float m = 0.f;
        for (int j = t; j < 4608; j += 512) m = fmaxf(m, fabsf(w[j]));
        m = wave_max(m);
        if ((t & 63) == 0) red[t >> 6] = m;
        __syncthreads();
        float mall = red[0];
#pragma unroll
        for (int i = 1; i < 8; ++i) mall = fmaxf(mall, red[i]);
        float sc = mall / 127.0f;
        if (t == 0) wsc[co] = sc;
        int ci = t >> 6, cq = (t >> 4) & 3, cb = t & 15;
#pragma unroll
        for (int tap = 0; tap < 9; ++tap) {
            float q = fminf(fmaxf(rintf(w[t * 9 + tap] / sc), -128.f), 127.f);
            wq[(((size_t)(tap * 8 + ci) * 4 + cq) * 128 + co) * 16 + cb] = (signed char)q;
        }
    } else {
        float wbn = gamma[t] / sqrtf(var[t] + 1e-5f);
        float bbn = beta[t] - mean[t] * wbn;
        float m = wave_max(fabsf(wbn));
        if ((t & 63) == 0) red[t >> 6] = m;
        __syncthreads();
        float mall = red[0];
#pragma unroll
        for (int i = 1; i < 8; ++i) mall = fmaxf(mall, red[i]);
        float ws_bn = mall / 127.0f;
        float s_in  = asf[0];
        float bn_sf = ws_bn * s_in;
        float wint  = fminf(fmaxf(rintf(wbn / ws_bn), -128.f), 127.f);
        float bint  = rintf(bbn / bn_sf);
        ws_f[WS_A1 / 4 + t] = wint * bn_sf / s_in;  // x1 = fmaf(x, A1, B1)
        ws_f[WS_B1 / 4 + t] = bint * bn_sf;
        if (t == 0) ws_u[1] = 0u;  // absmax(y) bits
    }
}

// ---- kernel 2: quantize x to int8 [ci][cq][w'][16] halo layout -------------
// processes b in REVERSE so first reads hit the L3-resident tail of x.
__global__ __launch_bounds__(256) void k_xquant(
    const float4* __restrict__ x4, float* __restrict__ ws_f,
    unsigned* __restrict__ x2u, unsigned* __restrict__ zrowu) {
    int bb = 31 - (blockIdx.x >> 5), h = blockIdx.x & 31;
    const float* A1 = ws_f + WS_A1 / 4;
    const float* B1 = ws_f + WS_B1 / 4;
    const float* XMX = ws_f + WS_XMX / 4;
    const float* XMN = ws_f + WS_XMN / 4;
    int t = threadIdx.x;

    // s_act from per-channel stats (exact: fma monotone in x, relu clamp >=0)
    __shared__ float sred[4];
    float cand = 0.f;
#pragma unroll
    for (int c0 = 0; c0 < 512; c0 += 256) {
        int c = c0 + t;
        float A = A1[c], B = B1[c];
        cand = fmaxf(cand, fmaxf(fmaf(XMX[c], A, B), fmaf(XMN[c], A, B)));
    }
    cand = wave_max(cand);
    if ((t & 63) == 0) sred[t >> 6] = cand;
    __syncthreads();
    float xm = fmaxf(fmaxf(sred[0], sred[1]), fmaxf(sred[2], sred[3]));
    float inv_sact = 127.0f / xm;
    if (blockIdx.x == 0 && t == 0) ws_f[3] = xm / 127.0f;  // s_act for k_conv

    size_t rowd = (size_t)(bb * 32 + h) * 4352;  // dwords per (b,h) row
    // zero halo columns w'=0,33: 32 (ci,cq) x 2 sides x 4 dwords
    {
        int p = t >> 3, side = (t >> 2) & 1, d = t & 3;
        x2u[rowd + (p * 34 + side * 33) * 4 + d] = 0u;
    }
    // zero shared zero-row (17408 B) with blocks 0..16
    if (blockIdx.x < 17) {
        int idx = blockIdx.x * 256 + t;
        if (idx < 4352) zrowu[idx] = 0u;
    }

    __shared__ unsigned lds[512 * 9];  // [c][w4(8)] packed bytes, +1 pad

#pragma unroll
    for (int it = 0; it < 16; ++it) {
        int idx = it * 256 + t;
        int c = idx >> 3, f4 = idx & 7;
        float4 v = x4[((size_t)bb * 512 + c) * 256 + h * 8 + f4];
        float A = A1[c] * inv_sact, B = B1[c] * inv_sact;
        unsigned q0 = (unsigned)(int)fminf(rintf(fmaxf(fmaf(v.x, A, B), 0.f)), 127.f);
        unsigned q1 = (unsigned)(int)fminf(rintf(fmaxf(fmaf(v.y, A, B), 0.f)), 127.f);
        unsigned q2 = (unsigned)(int)fminf(rintf(fmaxf(fmaf(v.z, A, B), 0.f)), 127.f);
        unsigned q3 = (unsigned)(int)fminf(rintf(fmaxf(fmaf(v.w, A, B), 0.f)), 127.f);
        lds[c * 9 + f4] = q0 | (q1 << 8) | (q2 << 16) | (q3 << 24);
    }
    __syncthreads();

    // phase 2: byte-transpose into [ci][cq][w'][16B]; half-wave-contiguous
#pragma unroll
    for (int it = 0; it < 4; ++it) {
        int p = it * 8 + (t >> 5);   // 0..31 = ci*4+cq
        int s = (t >> 2) & 7;        // w4 group
        int k = t & 3;               // w = s*4+k, w' = w+1
        unsigned L[16];
#pragma unroll
        for (int j = 0; j < 16; ++j) L[j] = lds[(p * 16 + j) * 9 + s];
        uint4 o;
        unsigned* op = (unsigned*)&o;
#pragma unroll
        for (int d = 0; d < 4; ++d)
            op[d] = ((L[4 * d] >> (8 * k)) & 255u) |
                    (((L[4 * d + 1] >> (8 * k)) & 255u) << 8) |
                    (((L[4 * d + 2] >> (8 * k)) & 255u) << 16) |
                    (((L[4 * d + 3] >> (8 * k)) & 255u) << 24);
        *(uint4*)(x2u + rowd + (size_t)(p * 34 + s * 4 + 1 + k) * 4) = o;
    }
}

// ---- kernel 3: int8 3x3 conv via MFMA -------------------------------------
// block = tile (64px = rows h0,h0+1; 64co) x 4 K-quarter waves; 2-stage tree.
__global__ __launch_bounds__(256, 3) void k_conv(
    const unsigned char* __restrict__ x2, const unsigned char* __restrict__ zrow,
    const signed char* __restrict__ wq,
    const float* __restrict__ wsc, const float* __restrict__ ws_f,
    unsigned* __restrict__ amaxy, float* __restrict__ y) {
    __shared__ v4i red[2][1024];  // 32 KB
    int t = threadIdx.x;
    int lane = t & 63, kv = t >> 6;          // kv = K quarter 0..3
    int m = lane & 15, quad = lane >> 4;

    int bid = blockIdx.x;
    int tile = (bid & 7) * 128 + (bid >> 3); // XCD swizzle
    int ch = tile & 1;
    int rowpair = (tile >> 1) & 15;
    int bb = tile >> 5;
    int h0 = rowpair * 2;
    int co0 = ch * 64;

    const unsigned char* xb = x2 + (size_t)bb * (32 * 17408);
    const v4i* rp[4];
#pragma unroll
    for (int j = 0; j < 4; ++j) {
        int row = h0 - 1 + j;
        rp[j] = (const v4i*)(((unsigned)row < 32u) ? (xb + (size_t)row * 17408) : zrow);
    }

    v4i acc[4][4];
#pragma unroll
    for (int i = 0; i < 4; ++i)
#pragma unroll
        for (int j = 0; j < 4; ++j) acc[i][j] = (v4i){0, 0, 0, 0};

    const v4i* pw = (const v4i*)wq + quad * 128 + co0 + m;
    int abase = quad * 34 + m;

#pragma unroll
    for (int kh = 0; kh < 3; ++kh)
#pragma unroll
        for (int kw = 0; kw < 3; ++kw) {
            int tap = kh * 3 + kw;
#pragma unroll
            for (int cc = 0; cc < 2; ++cc) {
                int ci = kv * 2 + cc;
                v4i a[4];
#pragma unroll
                for (int mt = 0; mt < 4; ++mt)
                    a[mt] = rp[kh + (mt >> 1)][ci * 136 + abase + kw + (mt & 1) * 16];
#pragma unroll
                for (int nt = 0; nt < 4; ++nt) {
                    v4i bf = pw[(tap * 8 + ci) * 512 + nt * 16];
#pragma unroll
                    for (int mt = 0; mt < 4; ++mt)
                        acc[mt][nt] = __builtin_amdgcn_mfma_i32_16x16x64_i8(a[mt], bf, acc[mt][nt], 0, 0, 0);
                }
            }
        }

    // 2-stage tree combine of the 4 K-quarters
    if (kv >= 2) {
#pragma unroll
        for (int mt = 0; mt < 4; ++mt)
#pragma unroll
            for (int nt = 0; nt < 4; ++nt)
                red[kv - 2][(mt * 4 + nt) * 64 + lane] = acc[mt][nt];
    }
    __syncthreads();
    if (kv < 2) {
#pragma unroll
        for (int mt = 0; mt < 4; ++mt)
#pragma unroll
            for (int nt = 0; nt < 4; ++nt) {
                v4i p = red[kv][(mt * 4 + nt) * 64 + lane];
                acc[mt][nt].x += p.x; acc[mt][nt].y += p.y;
                acc[mt][nt].z += p.z; acc[mt][nt].w += p.w;
            }
    }
    __syncthreads();
    if (kv == 1) {
#pragma unroll
        for (int mt = 0; mt < 4; ++mt)
#pragma unroll
            for (int nt = 0; nt < 4; ++nt)
                red[0][(mt * 4 + nt) * 64 + lane] = acc[mt][nt];
    }
    __syncthreads();
    if (kv == 0) {
#pragma unroll
        for (int mt = 0; mt < 4; ++mt)
#pragma unroll
            for (int nt = 0; nt < 4; ++nt) {
                v4i p = red[0][(mt * 4 + nt) * 64 + lane];
                acc[mt][nt].x += p.x; acc[mt][nt].y += p.y;
                acc[mt][nt].z += p.z; acc[mt][nt].w += p.w;
            }

        // epilogue: C layout col(lane&15)=co, row(quad*4+reg)=w
        float s_act = ws_f[3];
        float mx = 0.f;
#pragma unroll
        for (int nt = 0; nt < 4; ++nt) {
            int co = co0 + nt * 16 + m;
            float sf = s_act * wsc[co];
#pragma unroll
            for (int mt = 0; mt < 4; ++mt) {
                int row = h0 + (mt >> 1);
                float* yb = y + ((size_t)(bb * 128 + co)) * 1024 + row * 32 + (mt & 1) * 16;
                float4 vv;
                vv.x = (float)acc[mt][nt][0] * sf;
                vv.y = (float)acc[mt][nt][1] * sf;
                vv.z = (float)acc[mt][nt][2] * sf;
                vv.w = (float)acc[mt][nt][3] * sf;
                *(float4*)(yb + quad * 4) = vv;
                mx = fmaxf(mx, fmaxf(fmaxf(fabsf(vv.x), fabsf(vv.y)),
                                     fmaxf(fabsf(vv.z), fabsf(vv.w))));
            }
        }
        mx = wave_max(mx);
        if (lane == 0) atomicMax(amaxy, __float_as_uint(mx));
    }
}

// ---- kernel 4: final requant in place + write s_out -----------------------
__global__ __launch_bounds__(256) void k_yquant(float* __restrict__ yout,
                                                const unsigned* __restrict__ ws_u) {
    float s_out = __uint_as_float(ws_u[1]) / 127.0f;
    float4* y4 = (float4*)yout;
    int stride = gridDim.x * blockDim.x;
    for (int i = blockIdx.x * blockDim.x + threadIdx.x; i < 1048576; i += stride) {
        float4 v = y4[i];
        v.x = fminf(fmaxf(rintf(v.x / s_out), -128.f), 127.f) * s_out;
        v.y = fminf(fmaxf(rintf(v.y / s_out), -128.f), 127.f) * s_out;
        v.z = fminf(fmaxf(rintf(v.z / s_out), -128.f), 127.f) * s_out;
        v.w = fminf(fmaxf(rintf(v.w / s_out), -128.f), 127.f) * s_out;
        y4[i] = v;
    }
    if (blockIdx.x == 0 && threadIdx.x == 0) yout[4194304] = s_out;
}

extern "C" void kernel_launch(void* const* d_in, const int* in_sizes, int n_in,
                              void* d_out, int out_size, void* d_ws, size_t ws_size,
                              hipStream_t stream) {
    const float* x     = (const float*)d_in[0];
    const float* asf   = (const float*)d_in[1];
    const float* gamma = (const float*)d_in[2];
    const float* beta  = (const float*)d_in[3];
    const float* mean  = (const float*)d_in[4];
    const float* var   = (const float*)d_in[5];
    const float* cw    = (const float*)d_in[6];

    float*    ws_f = (float*)d_ws;
    unsigned* ws_u = (unsigned*)d_ws;
    signed char*   wq   = (signed char*)d_ws + WS_WQ;
    unsigned char* x2   = (unsigned char*)d_ws + WS_X2;
    unsigned char* zrow = (unsigned char*)d_ws + WS_ZROW;
    float* y = (float*)d_out;

    k_prep<<<641, 512, 0, stream>>>(gamma, beta, mean, var, asf, cw,
                                    (const float4*)x, ws_f, ws_u,
                                    ws_f + WS_WSC / 4, wq);
    k_xquant<<<1024, 256, 0, stream>>>((const float4*)x, ws_f,
                                       (unsigned*)x2, (unsigned*)zrow);
    k_conv<<<1024, 256, 0, stream>>>(x2, zrow, wq, ws_f + WS_WSC / 4,
                                     ws_f, ws_u + 1, y);
    k_yquant<<<1024, 256, 0, stream>>>(y, ws_u);
}

// Round 8
// 160.183 us; speedup vs baseline: 1.6272x; 1.0296x over previous
//
#include <hip/hip_runtime.h>

// ---------------------------------------------------------------------------
// Q_DenseLayer: BN-fold int8 affine -> ReLU -> per-tensor 8b quant ->
// int8 3x3 conv (MFMA i32_16x16x64_i8) -> per-tensor 8b requant.
// Shapes: x[32,512,32,32] f32, W[128,512,3,3] f32, out y[32,128,32,32] + s_out.
//
// R8: k_conv stages weights through LDS (global_load_lds width=16): block =
// 4 waves = 2 row-pairs x 2 K-halves sharing one 64-co B tile -> device B
// traffic 295->151 MB, L1/CU 2.3->1.7 MB. Grid 512, (256,2), 72KB LDS
// (B-stage, reused as K-combine buffer). R6/R7 layouts retained:
//   x2 [b][h][ci8][cq4][w'34][16B], wq [tap][ci][cq4][co128][16B].
// Fixed ~95us of timed harness work (256MiB ws poison + d_in restore) is
// outside our control; controllable kernel budget ~70us.
// ---------------------------------------------------------------------------

typedef int v4i __attribute__((ext_vector_type(4)));

// workspace byte offsets
#define WS_A1    64        // 512 f: A1_c = w_int*bn_sf/s_in
#define WS_B1    2112      // 512 f: B1_c = b_int*bn_sf
#define WS_WSC   4160      // 128 f
#define WS_XMX   4672      // 512 f: per-channel max(x)
#define WS_XMN   6720      // 512 f: per-channel min(x)
#define WS_WQ    8768      // 589824 i8: [tap][ci][cq][co128][16]
#define WS_X2    598592    // 17825792 u8: [b][h][ci][cq][w'34][16]
#define WS_ZROW  18424384  // 17408 u8 zero row
// ws_f[3] = s_act (k_xquant blk0), ws_u[1] = absmax(y) bits

__device__ __forceinline__ float wave_max(float m) {
#pragma unroll
    for (int off = 32; off; off >>= 1) m = fmaxf(m, __shfl_xor(m, off));
    return m;
}

// async global->LDS, 16B per lane: per-lane gsrc, wave-uniform LDS base
__device__ __forceinline__ void stage16(const char* g, char* s, int lane) {
#if defined(__has_builtin) && __has_builtin(__builtin_amdgcn_global_load_lds)
    __builtin_amdgcn_global_load_lds(
        (const __attribute__((address_space(1))) void*)g,
        (__attribute__((address_space(3))) void*)s, 16, 0, 0);
#else
    *(v4i*)(s + lane * 16) = *(const v4i*)g;
#endif
}

// ---- kernel 1: fused prep ---------------------------------------------------
// blocks 0..511:   per-channel x max/min (block c owns channel c)
// blocks 512..639: conv-weight quant (co = bid-512)
// block 640:       BN fold -> A1/B1
__global__ __launch_bounds__(512) void k_prep(
    const float* __restrict__ gamma, const float* __restrict__ beta,
    const float* __restrict__ mean,  const float* __restrict__ var,
    const float* __restrict__ asf,   const float* __restrict__ cw,
    const float4* __restrict__ x4,
    float* ws_f, unsigned* ws_u, float* __restrict__ wsc,
    signed char* __restrict__ wq) {
    int t = threadIdx.x;
    int bid = blockIdx.x;
    __shared__ float red[16];
    if (bid < 512) {
        int c = bid;
        float mx = -3.4e38f, mn = 3.4e38f;
#pragma unroll
        for (int r = 0; r < 16; ++r) {
            int bbb = r * 2 + (t >> 8);
            float4 v = x4[((size_t)(bbb * 512 + c)) * 256 + (t & 255)];
            mx = fmaxf(mx, fmaxf(fmaxf(v.x, v.y), fmaxf(v.z, v.w)));
            mn = fminf(mn, fminf(fminf(v.x, v.y), fminf(v.z, v.w)));
        }
        mx = wave_max(mx);
        mn = -wave_max(-mn);
        if ((t & 63) == 0) { red[t >> 6] = mx; red[8 + (t >> 6)] = mn; }
        __syncthreads();
        if (t == 0) {
            float M = red[0], N = red[8];
#pragma unroll
            for (int i = 1; i < 8; ++i) { M = fmaxf(M, red[i]); N = fminf(N, red[8 + i]); }
            ws_f[WS_XMX / 4 + c] = M;
            ws_f[WS_XMN / 4 + c] = N;
        }
    } else if (bid < 640) {
        int co = bid - 512;
        const float* w = cw + (size_t)co * 4608;
        float m = 0.f;
        for (int j = t; j < 4608; j += 512) m = fmaxf(m, fabsf(w[j]));
        m = wave_max(m);
        if ((t & 63) == 0) red[t >> 6] = m;
        __syncthreads();
        float mall = red[0];
#pragma unroll
        for (int i = 1; i < 8; ++i) mall = fmaxf(mall, red[i]);
        float sc = mall / 127.0f;
        if (t == 0) wsc[co] = sc;
        int ci = t >> 6, cq = (t >> 4) & 3, cb = t & 15;
#pragma unroll
        for (int tap = 0; tap < 9; ++tap) {
            float q = fminf(fmaxf(rintf(w[t * 9 + tap] / sc), -128.f), 127.f);
            wq[(((size_t)(tap * 8 + ci) * 4 + cq) * 128 + co) * 16 + cb] = (signed char)q;
        }
    } else {
        float wbn = gamma[t] / sqrtf(var[t] + 1e-5f);
        float bbn = beta[t] - mean[t] * wbn;
        float m = wave_max(fabsf(wbn));
        if ((t & 63) == 0) red[t >> 6] = m;
        __syncthreads();
        float mall = red[0];
#pragma unroll
        for (int i = 1; i < 8; ++i) mall = fmaxf(mall, red[i]);
        float ws_bn = mall / 127.0f;
        float s_in  = asf[0];
        float bn_sf = ws_bn * s_in;
        float wint  = fminf(fmaxf(rintf(wbn / ws_bn), -128.f), 127.f);
        float bint  = rintf(bbn / bn_sf);
        ws_f[WS_A1 / 4 + t] = wint * bn_sf / s_in;  // x1 = fmaf(x, A1, B1)
        ws_f[WS_B1 / 4 + t] = bint * bn_sf;
        if (t == 0) ws_u[1] = 0u;  // absmax(y) bits
    }
}

// ---- kernel 2: quantize x to int8 [ci][cq][w'][16] halo layout -------------
__global__ __launch_bounds__(256) void k_xquant(
    const float4* __restrict__ x4, float* __restrict__ ws_f,
    unsigned* __restrict__ x2u, unsigned* __restrict__ zrowu) {
    int bb = 31 - (blockIdx.x >> 5), h = blockIdx.x & 31;
    const float* A1 = ws_f + WS_A1 / 4;
    const float* B1 = ws_f + WS_B1 / 4;
    const float* XMX = ws_f + WS_XMX / 4;
    const float* XMN = ws_f + WS_XMN / 4;
    int t = threadIdx.x;

    // s_act from per-channel stats (exact: fma monotone in x, relu clamp >=0)
    __shared__ float sred[4];
    float cand = 0.f;
#pragma unroll
    for (int c0 = 0; c0 < 512; c0 += 256) {
        int c = c0 + t;
        float A = A1[c], B = B1[c];
        cand = fmaxf(cand, fmaxf(fmaf(XMX[c], A, B), fmaf(XMN[c], A, B)));
    }
    cand = wave_max(cand);
    if ((t & 63) == 0) sred[t >> 6] = cand;
    __syncthreads();
    float xm = fmaxf(fmaxf(sred[0], sred[1]), fmaxf(sred[2], sred[3]));
    float inv_sact = 127.0f / xm;
    if (blockIdx.x == 0 && t == 0) ws_f[3] = xm / 127.0f;  // s_act for k_conv

    size_t rowd = (size_t)(bb * 32 + h) * 4352;  // dwords per (b,h) row
    // zero halo columns w'=0,33
    {
        int p = t >> 3, side = (t >> 2) & 1, d = t & 3;
        x2u[rowd + (p * 34 + side * 33) * 4 + d] = 0u;
    }
    if (blockIdx.x < 17) {
        int idx = blockIdx.x * 256 + t;
        if (idx < 4352) zrowu[idx] = 0u;
    }

    __shared__ unsigned lds[512 * 9];  // [c][w4(8)] packed bytes, +1 pad

#pragma unroll
    for (int it = 0; it < 16; ++it) {
        int idx = it * 256 + t;
        int c = idx >> 3, f4 = idx & 7;
        float4 v = x4[((size_t)bb * 512 + c) * 256 + h * 8 + f4];
        float A = A1[c] * inv_sact, B = B1[c] * inv_sact;
        unsigned q0 = (unsigned)(int)fminf(rintf(fmaxf(fmaf(v.x, A, B), 0.f)), 127.f);
        unsigned q1 = (unsigned)(int)fminf(rintf(fmaxf(fmaf(v.y, A, B), 0.f)), 127.f);
        unsigned q2 = (unsigned)(int)fminf(rintf(fmaxf(fmaf(v.z, A, B), 0.f)), 127.f);
        unsigned q3 = (unsigned)(int)fminf(rintf(fmaxf(fmaf(v.w, A, B), 0.f)), 127.f);
        lds[c * 9 + f4] = q0 | (q1 << 8) | (q2 << 16) | (q3 << 24);
    }
    __syncthreads();

#pragma unroll
    for (int it = 0; it < 4; ++it) {
        int p = it * 8 + (t >> 5);   // 0..31 = ci*4+cq
        int s = (t >> 2) & 7;        // w4 group
        int k = t & 3;               // w = s*4+k, w' = w+1
        unsigned L[16];
#pragma unroll
        for (int j = 0; j < 16; ++j) L[j] = lds[(p * 16 + j) * 9 + s];
        uint4 o;
        unsigned* op = (unsigned*)&o;
#pragma unroll
        for (int d = 0; d < 4; ++d)
            op[d] = ((L[4 * d] >> (8 * k)) & 255u) |
                    (((L[4 * d + 1] >> (8 * k)) & 255u) << 8) |
                    (((L[4 * d + 2] >> (8 * k)) & 255u) << 16) |
                    (((L[4 * d + 3] >> (8 * k)) & 255u) << 24);
        *(uint4*)(x2u + rowd + (size_t)(p * 34 + s * 4 + 1 + k) * 4) = o;
    }
}

// ---- kernel 3: int8 3x3 conv, B staged through LDS ------------------------
// block = 4 waves = (rp in {0,1} row-pairs) x (kv in {0,1} K-halves), 64 co.
// grid 512 (XCD-swizzled), 2 blocks/CU. LDS 72KB: B stage (2 ci-slots of
// 36KB), reused as K-combine buffer (32KB) after the main loop.
__global__ __launch_bounds__(256, 2) void k_conv(
    const unsigned char* __restrict__ x2, const unsigned char* __restrict__ zrow,
    const signed char* __restrict__ wq,
    const float* __restrict__ wsc, const float* __restrict__ ws_f,
    unsigned* __restrict__ amaxy, float* __restrict__ y) {
    __shared__ char ldsb[73728];
    int t = threadIdx.x;
    int lane = t & 63, wv = t >> 6;
    int kv = wv & 1, rp = wv >> 1;
    int m = lane & 15, quad = lane >> 4;

    int bid = blockIdx.x;
    int tile = (bid & 7) * 64 + (bid >> 3);  // XCD swizzle, 64 tiles/XCD
    int ch = tile & 1;
    int rg = (tile >> 1) & 7;                // row-group of 4 rows
    int bb = tile >> 4;
    int co0 = ch * 64;
    int h0 = rg * 4 + rp * 2;                // this wave's first output row

    const unsigned char* xb = x2 + (size_t)bb * (32 * 17408);
    const v4i* rpt[4];
#pragma unroll
    for (int j = 0; j < 4; ++j) {
        int row = h0 - 1 + j;
        rpt[j] = (const v4i*)(((unsigned)row < 32u) ? (xb + (size_t)row * 17408) : zrow);
    }

    v4i acc[4][4];
#pragma unroll
    for (int i = 0; i < 4; ++i)
#pragma unroll
        for (int j = 0; j < 4; ++j) acc[i][j] = (v4i){0, 0, 0, 0};

    int abase = quad * 34 + m;

    for (int j = 0; j < 4; ++j) {
        // stage B for ci = j (kv0 slot) and ci = 4+j (kv1 slot): 72 chunks of
        // 1KB, 18 per wave. chunk c -> (kvs, tap, cq).
#pragma unroll
        for (int i = 0; i < 18; ++i) {
            int c = wv * 18 + i;
            int kvs = (c >= 36) ? 1 : 0;
            int rem = c - kvs * 36;
            int tap = rem >> 2, cq = rem & 3;
            int ci = kvs * 4 + j;
            const char* g = (const char*)wq +
                ((((size_t)(tap * 8 + ci) * 4 + cq) * 128 + co0) * 16) + lane * 16;
            char* s = ldsb + (((kvs * 9 + tap) * 4 + cq) << 10);
            stage16(g, s, lane);
        }
        __syncthreads();

        int ci = kv * 4 + j;
        const v4i* bbase = (const v4i*)ldsb + kv * 2304;  // 9*4*64 v4i per slot
#pragma unroll
        for (int kh = 0; kh < 3; ++kh)
#pragma unroll
            for (int kw = 0; kw < 3; ++kw) {
                int tap = kh * 3 + kw;
                v4i a[4];
#pragma unroll
                for (int mt = 0; mt < 4; ++mt)
                    a[mt] = rpt[kh + (mt >> 1)][ci * 136 + abase + kw + (mt & 1) * 16];
#pragma unroll
                for (int nt = 0; nt < 4; ++nt) {
                    v4i bf = bbase[(tap * 4 + quad) * 64 + nt * 16 + m];
#pragma unroll
                    for (int mt = 0; mt < 4; ++mt)
                        acc[mt][nt] = __builtin_amdgcn_mfma_i32_16x16x64_i8(a[mt], bf, acc[mt][nt], 0, 0, 0);
                }
            }
        __syncthreads();
    }

    // K-combine: kv=1 waves publish, kv=0 waves add (reuse stage LDS, 32KB)
    v4i* red = (v4i*)ldsb;
    if (kv == 1) {
#pragma unroll
        for (int mt = 0; mt < 4; ++mt)
#pragma unroll
            for (int nt = 0; nt < 4; ++nt)
                red[((rp * 16 + mt * 4 + nt) << 6) + lane] = acc[mt][nt];
    }
    __syncthreads();
    if (kv == 0) {
#pragma unroll
        for (int mt = 0; mt < 4; ++mt)
#pragma unroll
            for (int nt = 0; nt < 4; ++nt) {
                v4i p = red[((rp * 16 + mt * 4 + nt) << 6) + lane];
                acc[mt][nt].x += p.x; acc[mt][nt].y += p.y;
                acc[mt][nt].z += p.z; acc[mt][nt].w += p.w;
            }

        // epilogue: C layout col(lane&15)=co, row(quad*4+reg)=w
        float s_act = ws_f[3];
        float mx = 0.f;
#pragma unroll
        for (int nt = 0; nt < 4; ++nt) {
            int co = co0 + nt * 16 + m;
            float sf = s_act * wsc[co];
#pragma unroll
            for (int mt = 0; mt < 4; ++mt) {
                int row = h0 + (mt >> 1);
                float* yb = y + ((size_t)(bb * 128 + co)) * 1024 + row * 32 + (mt & 1) * 16;
                float4 vv;
                vv.x = (float)acc[mt][nt][0] * sf;
                vv.y = (float)acc[mt][nt][1] * sf;
                vv.z = (float)acc[mt][nt][2] * sf;
                vv.w = (float)acc[mt][nt][3] * sf;
                *(float4*)(yb + quad * 4) = vv;
                mx = fmaxf(mx, fmaxf(fmaxf(fabsf(vv.x), fabsf(vv.y)),
                                     fmaxf(fabsf(vv.z), fabsf(vv.w))));
            }
        }
        mx = wave_max(mx);
        if (lane == 0) atomicMax(amaxy, __float_as_uint(mx));
    }
}

// ---- kernel 4: final requant in place + write s_out -----------------------
__global__ __launch_bounds__(256) void k_yquant(float* __restrict__ yout,
                                                const unsigned* __restrict__ ws_u) {
    float s_out = __uint_as_float(ws_u[1]) / 127.0f;
    float4* y4 = (float4*)yout;
    int stride = gridDim.x * blockDim.x;
    for (int i = blockIdx.x * blockDim.x + threadIdx.x; i < 1048576; i += stride) {
        float4 v = y4[i];
        v.x = fminf(fmaxf(rintf(v.x / s_out), -128.f), 127.f) * s_out;
        v.y = fminf(fmaxf(rintf(v.y / s_out), -128.f), 127.f) * s_out;
        v.z = fminf(fmaxf(rintf(v.z / s_out), -128.f), 127.f) * s_out;
        v.w = fminf(fmaxf(rintf(v.w / s_out), -128.f), 127.f) * s_out;
        y4[i] = v;
    }
    if (blockIdx.x == 0 && threadIdx.x == 0) yout[4194304] = s_out;
}

extern "C" void kernel_launch(void* const* d_in, const int* in_sizes, int n_in,
                              void* d_out, int out_size, void* d_ws, size_t ws_size,
                              hipStream_t stream) {
    const float* x     = (const float*)d_in[0];
    const float* asf   = (const float*)d_in[1];
    const float* gamma = (const float*)d_in[2];
    const float* beta  = (const float*)d_in[3];
    const float* mean  = (const float*)d_in[4];
    const float* var   = (const float*)d_in[5];
    const float* cw    = (const float*)d_in[6];

    float*    ws_f = (float*)d_ws;
    unsigned* ws_u = (unsigned*)d_ws;
    signed char*   wq   = (signed char*)d_ws + WS_WQ;
    unsigned char* x2   = (unsigned char*)d_ws + WS_X2;
    unsigned char* zrow = (unsigned char*)d_ws + WS_ZROW;
    float* y = (float*)d_out;

    k_prep<<<641, 512, 0, stream>>>(gamma, beta, mean, var, asf, cw,
                                    (const float4*)x, ws_f, ws_u,
                                    ws_f + WS_WSC / 4, wq);
    k_xquant<<<1024, 256, 0, stream>>>((const float4*)x, ws_f,
                                       (unsigned*)x2, (unsigned*)zrow);
    k_conv<<<512, 256, 0, stream>>>(x2, zrow, wq, ws_f + WS_WSC / 4,
                                    ws_f, ws_u + 1, y);
    k_yquant<<<1024, 256, 0, stream>>>(y, ws_u);
}